// Round 15
// baseline (218.167 us; speedup 1.0000x reference)
//
#include <hip/hip_runtime.h>
#include <hip/hip_bf16.h>
#include <math.h>

#define NB 8
#define NC 256
#define NHW 2304
#define NH 4
#define HD 64
#define CPG 8
#define GN_EPS 1e-5f

typedef __bf16 bf16;
typedef __bf16 bf16x4 __attribute__((ext_vector_type(4)));
typedef __bf16 bf16x8 __attribute__((ext_vector_type(8)));
typedef float f32x4 __attribute__((ext_vector_type(4)));
typedef float f32x16 __attribute__((ext_vector_type(16)));
typedef int i32x4 __attribute__((ext_vector_type(4)));
typedef unsigned int u32;

#define MFMA16(a, b, c) __builtin_amdgcn_mfma_f32_16x16x32_bf16(a, b, c, 0, 0, 0)
#define MFMA32(a, b, c) __builtin_amdgcn_mfma_f32_32x32x16_bf16(a, b, c, 0, 0, 0)

// fast 2^x: raw v_exp_f32 (exact for our |x| <~ 40 range)
__device__ __forceinline__ float fexp2(float x) {
  float r;
  asm("v_exp_f32 %0, %1" : "=v"(r) : "v"(x));
  return r;
}

// ---------------- fused: weight fp32->bf16 (blocks 0..767) + GroupNorm ------
__global__ __launch_bounds__(256) void k_pre(const float* __restrict__ x,
                                             const float* __restrict__ gw,
                                             const float* __restrict__ gb,
                                             const float* __restrict__ qw,
                                             const float* __restrict__ pw,
                                             bf16* __restrict__ xnt,
                                             bf16* __restrict__ wq,
                                             bf16* __restrict__ wp) {
  int t = threadIdx.x;
  if (blockIdx.x < 768) {
    int i = blockIdx.x * 256 + t;
    wq[i] = (bf16)qw[i];
    if (i < NC * NC) wp[i] = (bf16)pw[i];
    return;
  }
  int bid = blockIdx.x - 768;
  int b = bid >> 5;
  int g = bid & 31;
  int c0 = g * CPG;
  const float* xb = x + (b * NC + c0) * NHW;
  float v[CPG][9];
  float s = 0.f, s2 = 0.f;
#pragma unroll
  for (int cc = 0; cc < CPG; ++cc)
#pragma unroll
    for (int k = 0; k < 9; ++k) {
      float val = xb[cc * NHW + k * 256 + t];
      v[cc][k] = val;
      s += val;
      s2 += val * val;
    }
#pragma unroll
  for (int m = 1; m < 64; m <<= 1) {
    s += __shfl_xor(s, m);
    s2 += __shfl_xor(s2, m);
  }
  __shared__ float red[8];
  int wid = t >> 6;
  if ((t & 63) == 0) { red[wid] = s; red[4 + wid] = s2; }
  __syncthreads();
  s = red[0] + red[1] + red[2] + red[3];
  s2 = red[4] + red[5] + red[6] + red[7];
  const float inv_n = 1.0f / (CPG * NHW);
  float mean = s * inv_n;
  float var = s2 * inv_n - mean * mean;
  float rsq = rsqrtf(var + GN_EPS);
  float ka[CPG], kb[CPG];
#pragma unroll
  for (int cc = 0; cc < CPG; ++cc) {
    float wv = gw[c0 + cc];
    ka[cc] = wv * rsq;
    kb[cc] = gb[c0 + cc] - mean * rsq * wv;
  }
  bf16* dst = xnt + b * NHW * NC + c0;
#pragma unroll
  for (int k = 0; k < 9; ++k) {
    bf16x8 o;
#pragma unroll
    for (int cc = 0; cc < CPG; ++cc)
      o[cc] = (bf16)(v[cc][k] * ka[cc] + kb[cc]);
    *reinterpret_cast<bf16x8*>(dst + (k * 256 + t) * NC) = o;
  }
}

// ---------------- QKV GEMM: M=hw(i), N=768(o), K=256(c) ----------------
__global__ __launch_bounds__(256) void k_qkv(const bf16* __restrict__ xnt,
                                             const bf16* __restrict__ wq,
                                             const float* __restrict__ qkvb,
                                             bf16* __restrict__ qt,
                                             bf16* __restrict__ kt,
                                             bf16* __restrict__ vv) {
  int b = blockIdx.z;
  int i_base = blockIdx.x * 128;
  int o_base = blockIdx.y * 128;
  int t = threadIdx.x;
  int lane = t & 63, wid = t >> 6;
  int wm = (wid >> 1) * 64, wn = (wid & 1) * 64;
  int l15 = lane & 15, g = lane >> 4;
  const bool qk = (o_base < 512);
  const bf16* ab;
  const bf16* bb;
  if (qk) {
    ab = wq + (o_base + wm + l15) * NC + g * 8;
    bb = xnt + ((size_t)b * NHW + i_base + wn + l15) * NC + g * 8;
  } else {
    ab = xnt + ((size_t)b * NHW + i_base + wm + l15) * NC + g * 8;
    bb = wq + (o_base + wn + l15) * NC + g * 8;
  }
  f32x4 acc[4][4] = {};
#pragma unroll 2
  for (int kc = 0; kc < 8; ++kc) {
    bf16x8 af[4], bf[4];
#pragma unroll
    for (int mf = 0; mf < 4; ++mf)
      af[mf] = *reinterpret_cast<const bf16x8*>(ab + mf * 16 * NC + kc * 32);
#pragma unroll
    for (int nf = 0; nf < 4; ++nf)
      bf[nf] = *reinterpret_cast<const bf16x8*>(bb + nf * 16 * NC + kc * 32);
#pragma unroll
    for (int mf = 0; mf < 4; ++mf)
#pragma unroll
      for (int nf = 0; nf < 4; ++nf)
        acc[mf][nf] = MFMA16(af[mf], bf[nf], acc[mf][nf]);
  }
  if (qk) {
    const float qscale = 0.125f * 1.4426950408889634f;
#pragma unroll
    for (int mf = 0; mf < 4; ++mf) {
      int o0 = o_base + wm + mf * 16 + g * 4;  // rows o0..o0+3
      f32x4 b4 = *reinterpret_cast<const f32x4*>(qkvb + o0);
      bool isQ = (o0 < 256);
      float sc = isQ ? qscale : 1.0f;
      int oo = isQ ? o0 : o0 - 256;
      bf16* base = (isQ ? qt : kt) +
                   ((size_t)(b * NH + (oo >> 6)) * NHW) * HD + (oo & 63);
#pragma unroll
      for (int nf = 0; nf < 4; ++nf) {
        int i = i_base + wn + nf * 16 + l15;
        bf16x4 w;
#pragma unroll
        for (int r = 0; r < 4; ++r)
          w[r] = (bf16)((acc[mf][nf][r] + b4[r]) * sc);
        *reinterpret_cast<bf16x4*>(base + (size_t)i * HD) = w;
      }
    }
  } else {
#pragma unroll
    for (int nf = 0; nf < 4; ++nf) {
      int og = o_base + wn + nf * 16 + l15;  // 512..767
      float bias = qkvb[og];
      int o2 = og - 512;
      bf16* dp = vv + ((size_t)(b * NH + (o2 >> 6)) * HD + (o2 & 63)) * NHW +
                 i_base + wm + g * 4;
#pragma unroll
      for (int mf = 0; mf < 4; ++mf) {
        bf16x4 w;
#pragma unroll
        for (int r = 0; r < 4; ++r) w[r] = (bf16)(acc[mf][nf][r] + bias);
        *reinterpret_cast<bf16x4*>(dp + mf * 16) = w;
      }
    }
  }
}

// ---------------- flash attention: hybrid K-direct-global / V-staged-LDS ----
// r13 base (512 thr, 8 waves = ig 0..3 x jsub 0..1, 128i x 64j tiles, grid
// 576 = 8 XCD x 72). Change: K fragments come DIRECT from global (kt layout
// [j][hd] IS the fragment layout; the 8KB tile is L1-resident so the 4
// ig-waves' identical reads dedup in L1) with register double-buffer one
// tile ahead, issue pinned by sched_barrier(0) (r6's ping-pong collapsed
// without pinning). V keeps the r13 LDS dbuf path (layout transform needed).
// LDS ops/tile/wave 12 -> ~6; LDS 32 -> 17.4 KB. Zero-max softmax unchanged.
// launch_bounds(512,3): VGPR cap 170, est ~135 (no spill — r8 lesson).
__global__ __launch_bounds__(512, 3) void k_attn(const bf16* __restrict__ qt,
                                                 const bf16* __restrict__ kt,
                                                 const bf16* __restrict__ vv,
                                                 bf16* __restrict__ att) {
  __shared__ union SM {
    bf16 v[2][4096];     // 16 KB V dbuf
    float m[4][64][17];  // 17.4 KB merge (after loop)
  } smem;

  const int tid = threadIdx.x;
  const int wid = tid >> 6, lane = tid & 63;
  const int l31 = lane & 31, g2 = lane >> 5;
  const int ig = wid & 3, jsub = wid >> 2;

  // bijective XCD swizzle: 576 blocks = 8 XCD x 72; each XCD gets 4 heads
  const int bid = blockIdx.x;
  const int wg = (bid & 7) * 72 + (bid >> 3);
  const int bh = wg / 18, it = wg % 18;
  const int b = bh >> 2, n = bh & 3;
  const int i0w = it * 128 + ig * 32;

  const bf16* qb = qt + (size_t)bh * NHW * HD;
  const bf16* kb = kt + (size_t)bh * NHW * HD;
  const bf16* vb = vv + (size_t)bh * HD * NHW;

  // V staging: 512 thr -> (r0 = row 0..63, cs = chunk 0..7), one 16B chunk
  const int r0 = tid >> 3, cs = tid & 7;
  const bf16* vg = vb + (size_t)r0 * NHW + cs * 8;
#define EOFF(c, row) ((c) * 512 + ((((row) + (c)) & 63) << 3))
  const int lw = EOFF(cs, r0);
  // V fragment offsets: chunk jsub*4+J*2+g2, rows l31 / l31+32
  int vsw0[2], vsw1[2];
#pragma unroll
  for (int J = 0; J < 2; ++J) {
    int c = jsub * 4 + J * 2 + g2;
    vsw0[J] = EOFF(c, l31);
    vsw1[J] = EOFF(c, l31 + 32);
  }
#undef EOFF

  // K fragments direct from global: row jsub*32+l31 (+jb), d = 16*kk + 8*g2
  const bf16* kfb = kb + (size_t)(jsub * 32 + l31) * HD + g2 * 8;

  // Q fragments: B-frag col i=l31, d = 16*kk + 8*g2 + e
  bf16x8 q[4];
#pragma unroll
  for (int kk = 0; kk < 4; ++kk)
    q[kk] = *reinterpret_cast<const bf16x8*>(qb + (i0w + l31) * HD + kk * 16 + g2 * 8);

  f32x16 acc0 = {}, acc1 = {};
  float l_r = 0.f;
  bf16x8 kA[4], kB[4];

  // prologue: stage V(0) into vbuf[0]; load K(0) into kA
  {
    bf16x8 d = *reinterpret_cast<const bf16x8*>(vg);
    *reinterpret_cast<bf16x8*>(&smem.v[0][lw]) = d;
  }
#pragma unroll
  for (int kk = 0; kk < 4; ++kk)
    kA[kk] = *reinterpret_cast<const bf16x8*>(kfb + kk * 16);
  asm volatile("s_waitcnt lgkmcnt(0)" ::: "memory");
  __builtin_amdgcn_s_barrier();

#define TILE_BODY(KF, VBUF)                                                   \
  {                                                                           \
    const bf16* vc = smem.v[VBUF];                                            \
    bf16x8 vf0[2], vf1[2];                                                    \
    _Pragma("unroll") for (int J = 0; J < 2; ++J) {                           \
      vf0[J] = *reinterpret_cast<const bf16x8*>(vc + vsw0[J]);                \
      vf1[J] = *reinterpret_cast<const bf16x8*>(vc + vsw1[J]);                \
    }                                                                         \
    f32x16 s = {};                                                            \
    __builtin_amdgcn_s_setprio(1);                                            \
    _Pragma("unroll") for (int kk = 0; kk < 4; ++kk) s =                      \
        MFMA32(KF[kk], q[kk], s);                                             \
    __builtin_amdgcn_s_setprio(0);                                            \
    u32 P[8];                                                                 \
    float la = 0.f, lb = 0.f;                                                 \
    _Pragma("unroll") for (int m = 0; m < 8; ++m) {                           \
      float e0 = fexp2(s[2 * m]);                                             \
      float e1 = fexp2(s[2 * m + 1]);                                         \
      la += e0;                                                               \
      lb += e1;                                                               \
      u32 pk;                                                                 \
      asm("v_cvt_pk_bf16_f32 %0, %1, %2" : "=v"(pk) : "v"(e0), "v"(e1));      \
      P[m] = pk;                                                              \
    }                                                                         \
    l_r += la + lb;                                                           \
    _Pragma("unroll") for (int J = 0; J < 2; ++J) {                           \
      u32 w0 = P[4 * J], w2 = P[4 * J + 2];                                   \
      asm("v_permlane32_swap_b32 %0, %1" : "+v"(w0), "+v"(w2));               \
      u32 w1 = P[4 * J + 1], w3 = P[4 * J + 3];                               \
      asm("v_permlane32_swap_b32 %0, %1" : "+v"(w1), "+v"(w3));               \
      i32x4 wv;                                                               \
      wv[0] = (int)w0; wv[1] = (int)w1; wv[2] = (int)w2; wv[3] = (int)w3;     \
      bf16x8 pf = __builtin_bit_cast(bf16x8, wv);                             \
      __builtin_amdgcn_s_setprio(1);                                          \
      acc0 = MFMA32(vf0[J], pf, acc0);                                        \
      acc1 = MFMA32(vf1[J], pf, acc1);                                        \
      __builtin_amdgcn_s_setprio(0);                                          \
    }                                                                         \
  }

  for (int tt = 0; tt < 36; tt += 2) {
    // ---- tile tt: uses kA, vbuf[0]; prefetch K(tt+1)->kB, V(tt+1)->regs ----
    bf16x8 vr = *reinterpret_cast<const bf16x8*>(vg + (tt + 1) * 64);
#pragma unroll
    for (int kk = 0; kk < 4; ++kk)
      kB[kk] = *reinterpret_cast<const bf16x8*>(
          kfb + (size_t)((tt + 1) * 64) * HD + kk * 16);
    __builtin_amdgcn_sched_barrier(0);  // pin prefetch issue before compute
    TILE_BODY(kA, 0)
    *reinterpret_cast<bf16x8*>(&smem.v[1][lw]) = vr;
    asm volatile("s_waitcnt lgkmcnt(0)" ::: "memory");
    __builtin_amdgcn_s_barrier();

    // ---- tile tt+1: uses kB, vbuf[1]; prefetch K(tt+2)->kA, V(tt+2) ----
    bf16x8 vr2;
    const bool more = (tt + 2 < 36);
    if (more) {
      vr2 = *reinterpret_cast<const bf16x8*>(vg + (tt + 2) * 64);
#pragma unroll
      for (int kk = 0; kk < 4; ++kk)
        kA[kk] = *reinterpret_cast<const bf16x8*>(
            kfb + (size_t)((tt + 2) * 64) * HD + kk * 16);
    }
    __builtin_amdgcn_sched_barrier(0);
    TILE_BODY(kB, 1)
    if (more) *reinterpret_cast<bf16x8*>(&smem.v[0][lw]) = vr2;
    asm volatile("s_waitcnt lgkmcnt(0)" ::: "memory");
    __builtin_amdgcn_s_barrier();
  }
#undef TILE_BODY

  // merge jsub halves (plain add, zero-max => no rescale), two phases
  if (jsub == 1) {
    float* mb = smem.m[ig][lane];
#pragma unroll
    for (int e = 0; e < 16; ++e) mb[e] = acc0[e];
    mb[16] = l_r;
  }
  __syncthreads();
  if (jsub == 0) {
    const float* mb = smem.m[ig][lane];
#pragma unroll
    for (int e = 0; e < 16; ++e) acc0[e] += mb[e];
    l_r += mb[16];
  }
  __syncthreads();
  if (jsub == 1) {
    float* mb = smem.m[ig][lane];
#pragma unroll
    for (int e = 0; e < 16; ++e) mb[e] = acc1[e];
  }
  __syncthreads();
  if (jsub == 0) {
    const float* mb = smem.m[ig][lane];
#pragma unroll
    for (int e = 0; e < 16; ++e) acc1[e] += mb[e];
    l_r += __shfl_xor(l_r, 32);
    const float inv = 1.0f / l_r;
    bf16* ob = att + ((size_t)(b * NHW) + i0w + l31) * NC + n * HD;
#pragma unroll
    for (int rq = 0; rq < 4; ++rq) {
      bf16x4 o0, o1;
#pragma unroll
      for (int c = 0; c < 4; ++c) {
        o0[c] = (bf16)(acc0[rq * 4 + c] * inv);
        o1[c] = (bf16)(acc1[rq * 4 + c] * inv);
      }
      *reinterpret_cast<bf16x4*>(ob + 8 * rq + 4 * g2) = o0;
      *reinterpret_cast<bf16x4*>(ob + 32 + 8 * rq + 4 * g2) = o1;
    }
  }
}

// ---------------- proj GEMM + bias + residual ----------------
__global__ __launch_bounds__(256) void k_proj(const bf16* __restrict__ att,
                                              const bf16* __restrict__ wp,
                                              const float* __restrict__ pb,
                                              const float* __restrict__ x,
                                              float* __restrict__ out) {
  int b = blockIdx.z;
  int i_base = blockIdx.x * 128;
  int o_base = blockIdx.y * 128;
  int t = threadIdx.x;
  int lane = t & 63, wid = t >> 6;
  int wm = (wid >> 1) * 64, wn = (wid & 1) * 64;
  int l15 = lane & 15, g = lane >> 4;
  const bf16* ab = wp + (o_base + wm + l15) * NC + g * 8;
  const bf16* bb = att + (b * NHW + i_base + wn + l15) * NC + g * 8;
  f32x4 acc[4][4] = {};
#pragma unroll 2
  for (int kc = 0; kc < 8; ++kc) {
    bf16x8 af[4], bf[4];
#pragma unroll
    for (int mf = 0; mf < 4; ++mf)
      af[mf] = *reinterpret_cast<const bf16x8*>(ab + mf * 16 * NC + kc * 32);
#pragma unroll
    for (int nf = 0; nf < 4; ++nf)
      bf[nf] = *reinterpret_cast<const bf16x8*>(bb + nf * 16 * NC + kc * 32);
#pragma unroll
    for (int mf = 0; mf < 4; ++mf)
#pragma unroll
      for (int nf = 0; nf < 4; ++nf)
        acc[mf][nf] = MFMA16(af[mf], bf[nf], acc[mf][nf]);
  }
  int orow0 = o_base + wm + g * 4;
#pragma unroll
  for (int mf = 0; mf < 4; ++mf)
#pragma unroll
    for (int r = 0; r < 4; ++r) {
      int o = orow0 + mf * 16 + r;
      float bias = pb[o];
      const float* xr = x + (b * NC + o) * NHW + i_base + wn;
      float* orow = out + (b * NC + o) * NHW + i_base + wn;
#pragma unroll
      for (int nf = 0; nf < 4; ++nf) {
        int i = nf * 16 + l15;
        orow[i] = acc[mf][nf][r] + bias + xr[i];
      }
    }
}

extern "C" void kernel_launch(void* const* d_in, const int* in_sizes, int n_in,
                              void* d_out, int out_size, void* d_ws, size_t ws_size,
                              hipStream_t stream) {
  const float* x    = (const float*)d_in[0];
  const float* gnw  = (const float*)d_in[1];
  const float* gnb  = (const float*)d_in[2];
  const float* qkvw = (const float*)d_in[3];
  const float* qkvb = (const float*)d_in[4];
  const float* pw   = (const float*)d_in[5];
  const float* pb   = (const float*)d_in[6];
  float* out = (float*)d_out;

  bf16* ws = (bf16*)d_ws;
  const size_t NE = (size_t)NB * NHW * NC;
  bf16* xnt = ws;
  bf16* qt  = ws + NE;
  bf16* kt  = ws + 2 * NE;
  bf16* vv  = ws + 3 * NE;
  bf16* att = ws + 4 * NE;
  bf16* wqb = ws + 5 * NE;
  bf16* wpb = wqb + 768 * 256;

  k_pre<<<1024, 256, 0, stream>>>(x, gnw, gnb, qkvw, pw, xnt, wqb, wpb);
  k_qkv<<<dim3(18, 6, NB), 256, 0, stream>>>(xnt, wqb, qkvb, qt, kt, vv);
  k_attn<<<576, 512, 0, stream>>>(qt, kt, vv, att);
  k_proj<<<dim3(18, 2, NB), 256, 0, stream>>>(att, wpb, pb, x, out);
}

// Round 16
// 163.419 us; speedup vs baseline: 1.3350x; 1.3350x over previous
//
#include <hip/hip_runtime.h>
#include <hip/hip_bf16.h>
#include <math.h>

#define NB 8
#define NC 256
#define NHW 2304
#define NH 4
#define HD 64
#define CPG 8
#define GN_EPS 1e-5f

typedef __bf16 bf16;
typedef __bf16 bf16x4 __attribute__((ext_vector_type(4)));
typedef __bf16 bf16x8 __attribute__((ext_vector_type(8)));
typedef float f32x4 __attribute__((ext_vector_type(4)));
typedef float f32x16 __attribute__((ext_vector_type(16)));
typedef int i32x4 __attribute__((ext_vector_type(4)));
typedef unsigned int u32;

#define MFMA16(a, b, c) __builtin_amdgcn_mfma_f32_16x16x32_bf16(a, b, c, 0, 0, 0)
#define MFMA32(a, b, c) __builtin_amdgcn_mfma_f32_32x32x16_bf16(a, b, c, 0, 0, 0)

// fast 2^x: raw v_exp_f32 (exact for our |x| <~ 40 range)
__device__ __forceinline__ float fexp2(float x) {
  float r;
  asm("v_exp_f32 %0, %1" : "=v"(r) : "v"(x));
  return r;
}

// ---------------- fused: weight fp32->bf16 (blocks 0..767) + GroupNorm ------
__global__ __launch_bounds__(256) void k_pre(const float* __restrict__ x,
                                             const float* __restrict__ gw,
                                             const float* __restrict__ gb,
                                             const float* __restrict__ qw,
                                             const float* __restrict__ pw,
                                             bf16* __restrict__ xnt,
                                             bf16* __restrict__ wq,
                                             bf16* __restrict__ wp) {
  int t = threadIdx.x;
  if (blockIdx.x < 768) {
    int i = blockIdx.x * 256 + t;
    wq[i] = (bf16)qw[i];
    if (i < NC * NC) wp[i] = (bf16)pw[i];
    return;
  }
  int bid = blockIdx.x - 768;
  int b = bid >> 5;
  int g = bid & 31;
  int c0 = g * CPG;
  const float* xb = x + (b * NC + c0) * NHW;
  float v[CPG][9];
  float s = 0.f, s2 = 0.f;
#pragma unroll
  for (int cc = 0; cc < CPG; ++cc)
#pragma unroll
    for (int k = 0; k < 9; ++k) {
      float val = xb[cc * NHW + k * 256 + t];
      v[cc][k] = val;
      s += val;
      s2 += val * val;
    }
#pragma unroll
  for (int m = 1; m < 64; m <<= 1) {
    s += __shfl_xor(s, m);
    s2 += __shfl_xor(s2, m);
  }
  __shared__ float red[8];
  int wid = t >> 6;
  if ((t & 63) == 0) { red[wid] = s; red[4 + wid] = s2; }
  __syncthreads();
  s = red[0] + red[1] + red[2] + red[3];
  s2 = red[4] + red[5] + red[6] + red[7];
  const float inv_n = 1.0f / (CPG * NHW);
  float mean = s * inv_n;
  float var = s2 * inv_n - mean * mean;
  float rsq = rsqrtf(var + GN_EPS);
  float ka[CPG], kb[CPG];
#pragma unroll
  for (int cc = 0; cc < CPG; ++cc) {
    float wv = gw[c0 + cc];
    ka[cc] = wv * rsq;
    kb[cc] = gb[c0 + cc] - mean * rsq * wv;
  }
  bf16* dst = xnt + b * NHW * NC + c0;
#pragma unroll
  for (int k = 0; k < 9; ++k) {
    bf16x8 o;
#pragma unroll
    for (int cc = 0; cc < CPG; ++cc)
      o[cc] = (bf16)(v[cc][k] * ka[cc] + kb[cc]);
    *reinterpret_cast<bf16x8*>(dst + (k * 256 + t) * NC) = o;
  }
}

// ---------------- QKV GEMM: M=hw(i), N=768(o), K=256(c) ----------------
__global__ __launch_bounds__(256) void k_qkv(const bf16* __restrict__ xnt,
                                             const bf16* __restrict__ wq,
                                             const float* __restrict__ qkvb,
                                             bf16* __restrict__ qt,
                                             bf16* __restrict__ kt,
                                             bf16* __restrict__ vv) {
  int b = blockIdx.z;
  int i_base = blockIdx.x * 128;
  int o_base = blockIdx.y * 128;
  int t = threadIdx.x;
  int lane = t & 63, wid = t >> 6;
  int wm = (wid >> 1) * 64, wn = (wid & 1) * 64;
  int l15 = lane & 15, g = lane >> 4;
  const bool qk = (o_base < 512);
  const bf16* ab;
  const bf16* bb;
  if (qk) {
    ab = wq + (o_base + wm + l15) * NC + g * 8;
    bb = xnt + ((size_t)b * NHW + i_base + wn + l15) * NC + g * 8;
  } else {
    ab = xnt + ((size_t)b * NHW + i_base + wm + l15) * NC + g * 8;
    bb = wq + (o_base + wn + l15) * NC + g * 8;
  }
  f32x4 acc[4][4] = {};
#pragma unroll 2
  for (int kc = 0; kc < 8; ++kc) {
    bf16x8 af[4], bf[4];
#pragma unroll
    for (int mf = 0; mf < 4; ++mf)
      af[mf] = *reinterpret_cast<const bf16x8*>(ab + mf * 16 * NC + kc * 32);
#pragma unroll
    for (int nf = 0; nf < 4; ++nf)
      bf[nf] = *reinterpret_cast<const bf16x8*>(bb + nf * 16 * NC + kc * 32);
#pragma unroll
    for (int mf = 0; mf < 4; ++mf)
#pragma unroll
      for (int nf = 0; nf < 4; ++nf)
        acc[mf][nf] = MFMA16(af[mf], bf[nf], acc[mf][nf]);
  }
  if (qk) {
    const float qscale = 0.125f * 1.4426950408889634f;
#pragma unroll
    for (int mf = 0; mf < 4; ++mf) {
      int o0 = o_base + wm + mf * 16 + g * 4;  // rows o0..o0+3
      f32x4 b4 = *reinterpret_cast<const f32x4*>(qkvb + o0);
      bool isQ = (o0 < 256);
      float sc = isQ ? qscale : 1.0f;
      int oo = isQ ? o0 : o0 - 256;
      bf16* base = (isQ ? qt : kt) +
                   ((size_t)(b * NH + (oo >> 6)) * NHW) * HD + (oo & 63);
#pragma unroll
      for (int nf = 0; nf < 4; ++nf) {
        int i = i_base + wn + nf * 16 + l15;
        bf16x4 w;
#pragma unroll
        for (int r = 0; r < 4; ++r)
          w[r] = (bf16)((acc[mf][nf][r] + b4[r]) * sc);
        *reinterpret_cast<bf16x4*>(base + (size_t)i * HD) = w;
      }
    }
  } else {
#pragma unroll
    for (int nf = 0; nf < 4; ++nf) {
      int og = o_base + wn + nf * 16 + l15;  // 512..767
      float bias = qkvb[og];
      int o2 = og - 512;
      bf16* dp = vv + ((size_t)(b * NH + (o2 >> 6)) * HD + (o2 & 63)) * NHW +
                 i_base + wm + g * 4;
#pragma unroll
      for (int mf = 0; mf < 4; ++mf) {
        bf16x4 w;
#pragma unroll
        for (int r = 0; r < 4; ++r) w[r] = (bf16)(acc[mf][nf][r] + bias);
        *reinterpret_cast<bf16x4*>(dp + mf * 16) = w;
      }
    }
  }
}

// ---------------- flash attention: r13 + T15 rotation -----------------------
// r13 base (512 thr, 8 waves = ig 0..3 x jsub 0..1, 128i x 64j tiles, 32KB
// LDS dbuf, grid 576 = 8 XCD x 72). Rotation: iteration t runs softmax(t-1)
// [VALU] alongside QK(t) + PV(t-1) [matrix pipe, 3 independent chains]; V
// staging lags K one tile (kbuf: t, vbuf: t-1) so PV(t-1) reads LDS directly.
// In r13's config occupancy is LDS-bound (2 blocks/CU), NOT VGPR-bound:
// rotation's +24 VGPR (56->~80, cap 128 at lb(512,4)) should be free, unlike
// r12 where it halved residency. One lgkm+barrier per tile as in r13.
__global__ __launch_bounds__(512, 4) void k_attn(const bf16* __restrict__ qt,
                                                 const bf16* __restrict__ kt,
                                                 const bf16* __restrict__ vv,
                                                 bf16* __restrict__ att) {
  __shared__ union SM {
    struct { bf16 k[2][4096]; bf16 v[2][4096]; } kv;  // 32 KB
    float m[4][64][17];                                // 17.4 KB (epilogue)
  } smem;

  const int tid = threadIdx.x;
  const int wid = tid >> 6, lane = tid & 63;
  const int l31 = lane & 31, g2 = lane >> 5;
  const int ig = wid & 3, jsub = wid >> 2;

  // bijective XCD swizzle: 576 blocks = 8 XCD x 72; each XCD gets 4 heads
  const int bid = blockIdx.x;
  const int wg = (bid & 7) * 72 + (bid >> 3);
  const int bh = wg / 18, it = wg % 18;
  const int b = bh >> 2, n = bh & 3;
  const int i0w = it * 128 + ig * 32;

  const bf16* qb = qt + (size_t)bh * NHW * HD;
  const bf16* kb = kt + (size_t)bh * NHW * HD;
  const bf16* vb = vv + (size_t)bh * HD * NHW;

  // staging: 512 thr -> (r0 = row 0..63, cs = chunk 0..7), 1 K + 1 V chunk
  const int r0 = tid >> 3, cs = tid & 7;
  const bf16* kg = kb + r0 * HD + cs * 8;
  const bf16* vg = vb + (size_t)r0 * NHW + cs * 8;
#define EOFF(c, row) ((c) * 512 + ((((row) + (c)) & 63) << 3))
  const int lw = EOFF(cs, r0);

  int ksw[4];
#pragma unroll
  for (int kk = 0; kk < 4; ++kk) ksw[kk] = EOFF(2 * kk + g2, jsub * 32 + l31);
  int vsw0[2], vsw1[2];
#pragma unroll
  for (int J = 0; J < 2; ++J) {
    int c = jsub * 4 + J * 2 + g2;
    vsw0[J] = EOFF(c, l31);
    vsw1[J] = EOFF(c, l31 + 32);
  }
#undef EOFF

  // Q fragments: B-frag col i=l31, d = 16*kk + 8*g2 + e
  bf16x8 q[4];
#pragma unroll
  for (int kk = 0; kk < 4; ++kk)
    q[kk] = *reinterpret_cast<const bf16x8*>(qb + (i0w + l31) * HD + kk * 16 + g2 * 8);

  f32x16 acc0 = {}, acc1 = {};
  f32x16 sO;
  float l_r = 0.f;

  // prologue: stage K(0) into kbuf[0]
  {
    bf16x8 a = *reinterpret_cast<const bf16x8*>(kg);
    *reinterpret_cast<bf16x8*>(&smem.kv.k[0][lw]) = a;
  }
  asm volatile("s_waitcnt lgkmcnt(0)" ::: "memory");
  __builtin_amdgcn_s_barrier();

  // ---- peeled t=0: QK(0) only; stage K(1)->kbuf[1], V(0)->vbuf[0] ----
  {
    bf16x8 kr = *reinterpret_cast<const bf16x8*>(kg + 64 * HD);
    bf16x8 vr = *reinterpret_cast<const bf16x8*>(vg);
    const bf16* kc = smem.kv.k[0];
    f32x16 s = {};
    __builtin_amdgcn_s_setprio(1);
#pragma unroll
    for (int kk = 0; kk < 4; ++kk) {
      bf16x8 kf = *reinterpret_cast<const bf16x8*>(kc + ksw[kk]);
      s = MFMA32(kf, q[kk], s);
    }
    __builtin_amdgcn_s_setprio(0);
    *reinterpret_cast<bf16x8*>(&smem.kv.k[1][lw]) = kr;
    *reinterpret_cast<bf16x8*>(&smem.kv.v[0][lw]) = vr;
    asm volatile("s_waitcnt lgkmcnt(0)" ::: "memory");
    __builtin_amdgcn_s_barrier();
    sO = s;
  }

  // ---- main loop: iteration t = softmax(t-1) + QK(t) + PV(t-1) ----
  for (int t = 1; t < 36; ++t) {
    bf16x8 kr, vr;
    if (t < 35)
      kr = *reinterpret_cast<const bf16x8*>(kg + (t + 1) * (64 * HD));
    vr = *reinterpret_cast<const bf16x8*>(vg + t * 64);

    const bf16* kc = smem.kv.k[t & 1];         // K(t)
    const bf16* vcp = smem.kv.v[(t - 1) & 1];  // V(t-1)

    bf16x8 kf[4], vf0[2], vf1[2];
#pragma unroll
    for (int kk = 0; kk < 4; ++kk)
      kf[kk] = *reinterpret_cast<const bf16x8*>(kc + ksw[kk]);
#pragma unroll
    for (int J = 0; J < 2; ++J) {
      vf0[J] = *reinterpret_cast<const bf16x8*>(vcp + vsw0[J]);
      vf1[J] = *reinterpret_cast<const bf16x8*>(vcp + vsw1[J]);
    }

    // softmax of s(t-1): VALU work independent of this tile's MFMAs
    u32 P[8];
    float la = 0.f, lb = 0.f;
#pragma unroll
    for (int m = 0; m < 8; ++m) {
      float e0 = fexp2(sO[2 * m]);
      float e1 = fexp2(sO[2 * m + 1]);
      la += e0;
      lb += e1;
      u32 pk;
      asm("v_cvt_pk_bf16_f32 %0, %1, %2" : "=v"(pk) : "v"(e0), "v"(e1));
      P[m] = pk;
    }
    l_r += la + lb;
    bf16x8 pf[2];
#pragma unroll
    for (int J = 0; J < 2; ++J) {
      u32 w0 = P[4 * J], w2 = P[4 * J + 2];
      asm("v_permlane32_swap_b32 %0, %1" : "+v"(w0), "+v"(w2));
      u32 w1 = P[4 * J + 1], w3 = P[4 * J + 3];
      asm("v_permlane32_swap_b32 %0, %1" : "+v"(w1), "+v"(w3));
      i32x4 wv;
      wv[0] = (int)w0; wv[1] = (int)w1; wv[2] = (int)w2; wv[3] = (int)w3;
      pf[J] = __builtin_bit_cast(bf16x8, wv);
    }

    // 3 independent MFMA chains: QK(t), PV acc0(t-1), PV acc1(t-1)
    f32x16 s = {};
    __builtin_amdgcn_s_setprio(1);
#pragma unroll
    for (int kk = 0; kk < 4; ++kk) s = MFMA32(kf[kk], q[kk], s);
#pragma unroll
    for (int J = 0; J < 2; ++J) {
      acc0 = MFMA32(vf0[J], pf[J], acc0);
      acc1 = MFMA32(vf1[J], pf[J], acc1);
    }
    __builtin_amdgcn_s_setprio(0);

    // staged writes: K(t+1) -> kbuf[(t+1)&1], V(t) -> vbuf[t&1]
    if (t < 35)
      *reinterpret_cast<bf16x8*>(&smem.kv.k[(t + 1) & 1][lw]) = kr;
    *reinterpret_cast<bf16x8*>(&smem.kv.v[t & 1][lw]) = vr;
    asm volatile("s_waitcnt lgkmcnt(0)" ::: "memory");
    __builtin_amdgcn_s_barrier();
    sO = s;
  }

  // ---- epilogue: softmax(35) + PV(35) from vbuf[1] ----
  {
    u32 P[8];
    float la = 0.f, lb = 0.f;
#pragma unroll
    for (int m = 0; m < 8; ++m) {
      float e0 = fexp2(sO[2 * m]);
      float e1 = fexp2(sO[2 * m + 1]);
      la += e0;
      lb += e1;
      u32 pk;
      asm("v_cvt_pk_bf16_f32 %0, %1, %2" : "=v"(pk) : "v"(e0), "v"(e1));
      P[m] = pk;
    }
    l_r += la + lb;
    const bf16* vcp = smem.kv.v[1];
#pragma unroll
    for (int J = 0; J < 2; ++J) {
      u32 w0 = P[4 * J], w2 = P[4 * J + 2];
      asm("v_permlane32_swap_b32 %0, %1" : "+v"(w0), "+v"(w2));
      u32 w1 = P[4 * J + 1], w3 = P[4 * J + 3];
      asm("v_permlane32_swap_b32 %0, %1" : "+v"(w1), "+v"(w3));
      i32x4 wv;
      wv[0] = (int)w0; wv[1] = (int)w1; wv[2] = (int)w2; wv[3] = (int)w3;
      bf16x8 pf = __builtin_bit_cast(bf16x8, wv);
      bf16x8 v0 = *reinterpret_cast<const bf16x8*>(vcp + vsw0[J]);
      bf16x8 v1 = *reinterpret_cast<const bf16x8*>(vcp + vsw1[J]);
      acc0 = MFMA32(v0, pf, acc0);
      acc1 = MFMA32(v1, pf, acc1);
    }
  }
  __builtin_amdgcn_s_barrier();

  // merge jsub halves (plain add, zero-max => no rescale), two phases
  if (jsub == 1) {
    float* mb = smem.m[ig][lane];
#pragma unroll
    for (int e = 0; e < 16; ++e) mb[e] = acc0[e];
    mb[16] = l_r;
  }
  __syncthreads();
  if (jsub == 0) {
    const float* mb = smem.m[ig][lane];
#pragma unroll
    for (int e = 0; e < 16; ++e) acc0[e] += mb[e];
    l_r += mb[16];
  }
  __syncthreads();
  if (jsub == 1) {
    float* mb = smem.m[ig][lane];
#pragma unroll
    for (int e = 0; e < 16; ++e) mb[e] = acc1[e];
  }
  __syncthreads();
  if (jsub == 0) {
    const float* mb = smem.m[ig][lane];
#pragma unroll
    for (int e = 0; e < 16; ++e) acc1[e] += mb[e];
    l_r += __shfl_xor(l_r, 32);
    const float inv = 1.0f / l_r;
    bf16* ob = att + ((size_t)(b * NHW) + i0w + l31) * NC + n * HD;
#pragma unroll
    for (int rq = 0; rq < 4; ++rq) {
      bf16x4 o0, o1;
#pragma unroll
      for (int c = 0; c < 4; ++c) {
        o0[c] = (bf16)(acc0[rq * 4 + c] * inv);
        o1[c] = (bf16)(acc1[rq * 4 + c] * inv);
      }
      *reinterpret_cast<bf16x4*>(ob + 8 * rq + 4 * g2) = o0;
      *reinterpret_cast<bf16x4*>(ob + 32 + 8 * rq + 4 * g2) = o1;
    }
  }
}

// ---------------- proj GEMM + bias + residual ----------------
__global__ __launch_bounds__(256) void k_proj(const bf16* __restrict__ att,
                                              const bf16* __restrict__ wp,
                                              const float* __restrict__ pb,
                                              const float* __restrict__ x,
                                              float* __restrict__ out) {
  int b = blockIdx.z;
  int i_base = blockIdx.x * 128;
  int o_base = blockIdx.y * 128;
  int t = threadIdx.x;
  int lane = t & 63, wid = t >> 6;
  int wm = (wid >> 1) * 64, wn = (wid & 1) * 64;
  int l15 = lane & 15, g = lane >> 4;
  const bf16* ab = wp + (o_base + wm + l15) * NC + g * 8;
  const bf16* bb = att + (b * NHW + i_base + wn + l15) * NC + g * 8;
  f32x4 acc[4][4] = {};
#pragma unroll 2
  for (int kc = 0; kc < 8; ++kc) {
    bf16x8 af[4], bf[4];
#pragma unroll
    for (int mf = 0; mf < 4; ++mf)
      af[mf] = *reinterpret_cast<const bf16x8*>(ab + mf * 16 * NC + kc * 32);
#pragma unroll
    for (int nf = 0; nf < 4; ++nf)
      bf[nf] = *reinterpret_cast<const bf16x8*>(bb + nf * 16 * NC + kc * 32);
#pragma unroll
    for (int mf = 0; mf < 4; ++mf)
#pragma unroll
      for (int nf = 0; nf < 4; ++nf)
        acc[mf][nf] = MFMA16(af[mf], bf[nf], acc[mf][nf]);
  }
  int orow0 = o_base + wm + g * 4;
#pragma unroll
  for (int mf = 0; mf < 4; ++mf)
#pragma unroll
    for (int r = 0; r < 4; ++r) {
      int o = orow0 + mf * 16 + r;
      float bias = pb[o];
      const float* xr = x + (b * NC + o) * NHW + i_base + wn;
      float* orow = out + (b * NC + o) * NHW + i_base + wn;
#pragma unroll
      for (int nf = 0; nf < 4; ++nf) {
        int i = nf * 16 + l15;
        orow[i] = acc[mf][nf][r] + bias + xr[i];
      }
    }
}

extern "C" void kernel_launch(void* const* d_in, const int* in_sizes, int n_in,
                              void* d_out, int out_size, void* d_ws, size_t ws_size,
                              hipStream_t stream) {
  const float* x    = (const float*)d_in[0];
  const float* gnw  = (const float*)d_in[1];
  const float* gnb  = (const float*)d_in[2];
  const float* qkvw = (const float*)d_in[3];
  const float* qkvb = (const float*)d_in[4];
  const float* pw   = (const float*)d_in[5];
  const float* pb   = (const float*)d_in[6];
  float* out = (float*)d_out;

  bf16* ws = (bf16*)d_ws;
  const size_t NE = (size_t)NB * NHW * NC;
  bf16* xnt = ws;
  bf16* qt  = ws + NE;
  bf16* kt  = ws + 2 * NE;
  bf16* vv  = ws + 3 * NE;
  bf16* att = ws + 4 * NE;
  bf16* wqb = ws + 5 * NE;
  bf16* wpb = wqb + 768 * 256;

  k_pre<<<1024, 256, 0, stream>>>(x, gnw, gnb, qkvw, pw, xnt, wqb, wpb);
  k_qkv<<<dim3(18, 6, NB), 256, 0, stream>>>(xnt, wqb, qkvb, qt, kt, vv);
  k_attn<<<576, 512, 0, stream>>>(qt, kt, vv, att);
  k_proj<<<dim3(18, 2, NB), 256, 0, stream>>>(att, wpb, pb, x, out);
}

// Round 17
// 143.865 us; speedup vs baseline: 1.5165x; 1.1359x over previous
//
#include <hip/hip_runtime.h>
#include <hip/hip_bf16.h>
#include <math.h>

#define NB 8
#define NC 256
#define NHW 2304
#define NH 4
#define HD 64
#define CPG 8
#define GN_EPS 1e-5f

typedef __bf16 bf16;
typedef __bf16 bf16x4 __attribute__((ext_vector_type(4)));
typedef __bf16 bf16x8 __attribute__((ext_vector_type(8)));
typedef float f32x4 __attribute__((ext_vector_type(4)));
typedef float f32x16 __attribute__((ext_vector_type(16)));
typedef int i32x4 __attribute__((ext_vector_type(4)));
typedef unsigned int u32;

#define MFMA16(a, b, c) __builtin_amdgcn_mfma_f32_16x16x32_bf16(a, b, c, 0, 0, 0)
#define MFMA32(a, b, c) __builtin_amdgcn_mfma_f32_32x32x16_bf16(a, b, c, 0, 0, 0)

// fast 2^x: raw v_exp_f32 (exact for our |x| <~ 40 range)
__device__ __forceinline__ float fexp2(float x) {
  float r;
  asm("v_exp_f32 %0, %1" : "=v"(r) : "v"(x));
  return r;
}

// ---------------- fused: weight fp32->bf16 (blocks 0..767) + GroupNorm ------
__global__ __launch_bounds__(256) void k_pre(const float* __restrict__ x,
                                             const float* __restrict__ gw,
                                             const float* __restrict__ gb,
                                             const float* __restrict__ qw,
                                             const float* __restrict__ pw,
                                             bf16* __restrict__ xnt,
                                             bf16* __restrict__ wq,
                                             bf16* __restrict__ wp) {
  int t = threadIdx.x;
  if (blockIdx.x < 768) {
    int i = blockIdx.x * 256 + t;
    wq[i] = (bf16)qw[i];
    if (i < NC * NC) wp[i] = (bf16)pw[i];
    return;
  }
  int bid = blockIdx.x - 768;
  int b = bid >> 5;
  int g = bid & 31;
  int c0 = g * CPG;
  const float* xb = x + (b * NC + c0) * NHW;
  float v[CPG][9];
  float s = 0.f, s2 = 0.f;
#pragma unroll
  for (int cc = 0; cc < CPG; ++cc)
#pragma unroll
    for (int k = 0; k < 9; ++k) {
      float val = xb[cc * NHW + k * 256 + t];
      v[cc][k] = val;
      s += val;
      s2 += val * val;
    }
#pragma unroll
  for (int m = 1; m < 64; m <<= 1) {
    s += __shfl_xor(s, m);
    s2 += __shfl_xor(s2, m);
  }
  __shared__ float red[8];
  int wid = t >> 6;
  if ((t & 63) == 0) { red[wid] = s; red[4 + wid] = s2; }
  __syncthreads();
  s = red[0] + red[1] + red[2] + red[3];
  s2 = red[4] + red[5] + red[6] + red[7];
  const float inv_n = 1.0f / (CPG * NHW);
  float mean = s * inv_n;
  float var = s2 * inv_n - mean * mean;
  float rsq = rsqrtf(var + GN_EPS);
  float ka[CPG], kb[CPG];
#pragma unroll
  for (int cc = 0; cc < CPG; ++cc) {
    float wv = gw[c0 + cc];
    ka[cc] = wv * rsq;
    kb[cc] = gb[c0 + cc] - mean * rsq * wv;
  }
  bf16* dst = xnt + b * NHW * NC + c0;
#pragma unroll
  for (int k = 0; k < 9; ++k) {
    bf16x8 o;
#pragma unroll
    for (int cc = 0; cc < CPG; ++cc)
      o[cc] = (bf16)(v[cc][k] * ka[cc] + kb[cc]);
    *reinterpret_cast<bf16x8*>(dst + (k * 256 + t) * NC) = o;
  }
}

// ---------------- QKV GEMM: M=hw(i), N=768(o), K=256(c) ----------------
__global__ __launch_bounds__(256) void k_qkv(const bf16* __restrict__ xnt,
                                             const bf16* __restrict__ wq,
                                             const float* __restrict__ qkvb,
                                             bf16* __restrict__ qt,
                                             bf16* __restrict__ kt,
                                             bf16* __restrict__ vv) {
  int b = blockIdx.z;
  int i_base = blockIdx.x * 128;
  int o_base = blockIdx.y * 128;
  int t = threadIdx.x;
  int lane = t & 63, wid = t >> 6;
  int wm = (wid >> 1) * 64, wn = (wid & 1) * 64;
  int l15 = lane & 15, g = lane >> 4;
  const bool qk = (o_base < 512);
  const bf16* ab;
  const bf16* bb;
  if (qk) {
    ab = wq + (o_base + wm + l15) * NC + g * 8;
    bb = xnt + ((size_t)b * NHW + i_base + wn + l15) * NC + g * 8;
  } else {
    ab = xnt + ((size_t)b * NHW + i_base + wm + l15) * NC + g * 8;
    bb = wq + (o_base + wn + l15) * NC + g * 8;
  }
  f32x4 acc[4][4] = {};
#pragma unroll 2
  for (int kc = 0; kc < 8; ++kc) {
    bf16x8 af[4], bf[4];
#pragma unroll
    for (int mf = 0; mf < 4; ++mf)
      af[mf] = *reinterpret_cast<const bf16x8*>(ab + mf * 16 * NC + kc * 32);
#pragma unroll
    for (int nf = 0; nf < 4; ++nf)
      bf[nf] = *reinterpret_cast<const bf16x8*>(bb + nf * 16 * NC + kc * 32);
#pragma unroll
    for (int mf = 0; mf < 4; ++mf)
#pragma unroll
      for (int nf = 0; nf < 4; ++nf)
        acc[mf][nf] = MFMA16(af[mf], bf[nf], acc[mf][nf]);
  }
  if (qk) {
    const float qscale = 0.125f * 1.4426950408889634f;
#pragma unroll
    for (int mf = 0; mf < 4; ++mf) {
      int o0 = o_base + wm + mf * 16 + g * 4;  // rows o0..o0+3
      f32x4 b4 = *reinterpret_cast<const f32x4*>(qkvb + o0);
      bool isQ = (o0 < 256);
      float sc = isQ ? qscale : 1.0f;
      int oo = isQ ? o0 : o0 - 256;
      bf16* base = (isQ ? qt : kt) +
                   ((size_t)(b * NH + (oo >> 6)) * NHW) * HD + (oo & 63);
#pragma unroll
      for (int nf = 0; nf < 4; ++nf) {
        int i = i_base + wn + nf * 16 + l15;
        bf16x4 w;
#pragma unroll
        for (int r = 0; r < 4; ++r)
          w[r] = (bf16)((acc[mf][nf][r] + b4[r]) * sc);
        *reinterpret_cast<bf16x4*>(base + (size_t)i * HD) = w;
      }
    }
  } else {
#pragma unroll
    for (int nf = 0; nf < 4; ++nf) {
      int og = o_base + wn + nf * 16 + l15;  // 512..767
      float bias = qkvb[og];
      int o2 = og - 512;
      bf16* dp = vv + ((size_t)(b * NH + (o2 >> 6)) * HD + (o2 & 63)) * NHW +
                 i_base + wm + g * 4;
#pragma unroll
      for (int mf = 0; mf < 4; ++mf) {
        bf16x4 w;
#pragma unroll
        for (int r = 0; r < 4; ++r) w[r] = (bf16)(acc[mf][nf][r] + bias);
        *reinterpret_cast<bf16x4*>(dp + mf * 16) = w;
      }
    }
  }
}

// ---------------- flash attention: r13 (best measured: 78.4us) --------------
// 512 thr, 8 waves = (ig 0..3, jsub 0..1), 128i x 64j tiles, 32KB LDS dbuf,
// chunk-major rotated layout elem(c,row) = c*512 + ((row+c)&63)*8, zero-max
// fexp2 softmax, permlane P->B-frags, one lgkm+barrier per tile. Grid 576 =
// 8 XCD x 72 (bijective swizzle, 4 heads/XCD L2-resident).
// Struck-out alternatives (measured): direct-global operands (r4/r6/r15),
// single-buffer (r10), T15 rotation (r12/r16: sO spills — WRITE_SIZE 2.4x),
// 64 rows/wave (r14: VGPR halves occupancy), lb(,6) (r8: catastrophic spill).
__global__ __launch_bounds__(512, 4) void k_attn(const bf16* __restrict__ qt,
                                                 const bf16* __restrict__ kt,
                                                 const bf16* __restrict__ vv,
                                                 bf16* __restrict__ att) {
  __shared__ union SM {
    struct { bf16 k[2][4096]; bf16 v[2][4096]; } kv;  // 32 KB
    float m[4][64][17];                                // 17.4 KB (epilogue)
  } smem;

  const int tid = threadIdx.x;
  const int wid = tid >> 6, lane = tid & 63;
  const int l31 = lane & 31, g2 = lane >> 5;
  const int ig = wid & 3, jsub = wid >> 2;

  // bijective XCD swizzle: 576 blocks = 8 XCD x 72; each XCD gets 4 heads
  const int bid = blockIdx.x;
  const int wg = (bid & 7) * 72 + (bid >> 3);
  const int bh = wg / 18, it = wg % 18;
  const int b = bh >> 2, n = bh & 3;
  const int i0w = it * 128 + ig * 32;

  const bf16* qb = qt + (size_t)bh * NHW * HD;
  const bf16* kb = kt + (size_t)bh * NHW * HD;
  const bf16* vb = vv + (size_t)bh * HD * NHW;

  // staging: 512 thr -> (r0 = row 0..63, cs = chunk 0..7), 1 K + 1 V chunk
  const int r0 = tid >> 3, cs = tid & 7;
  const bf16* kg = kb + r0 * HD + cs * 8;
  const bf16* vg = vb + (size_t)r0 * NHW + cs * 8;
#define EOFF(c, row) ((c) * 512 + ((((row) + (c)) & 63) << 3))
  const int lw = EOFF(cs, r0);

  // K fragment offsets: chunk 2kk+g2, rows jsub*32 + l31 (contiguous 512B)
  int ksw[4];
#pragma unroll
  for (int kk = 0; kk < 4; ++kk) ksw[kk] = EOFF(2 * kk + g2, jsub * 32 + l31);
  // V fragment offsets: chunk jsub*4+J*2+g2, rows l31 / l31+32
  int vsw0[2], vsw1[2];
#pragma unroll
  for (int J = 0; J < 2; ++J) {
    int c = jsub * 4 + J * 2 + g2;
    vsw0[J] = EOFF(c, l31);
    vsw1[J] = EOFF(c, l31 + 32);
  }
#undef EOFF

  // Q fragments: B-frag col i=l31, d = 16*kk + 8*g2 + e
  bf16x8 q[4];
#pragma unroll
  for (int kk = 0; kk < 4; ++kk)
    q[kk] = *reinterpret_cast<const bf16x8*>(qb + (i0w + l31) * HD + kk * 16 + g2 * 8);

  f32x16 acc0 = {}, acc1 = {};
  float l_r = 0.f;

  // prologue: stage tile 0 into buf 0
  {
    bf16x8 a = *reinterpret_cast<const bf16x8*>(kg);
    bf16x8 d = *reinterpret_cast<const bf16x8*>(vg);
    *reinterpret_cast<bf16x8*>(&smem.kv.k[0][lw]) = a;
    *reinterpret_cast<bf16x8*>(&smem.kv.v[0][lw]) = d;
  }
  asm volatile("s_waitcnt lgkmcnt(0)" ::: "memory");
  __builtin_amdgcn_s_barrier();

  for (int t = 0; t < 36; ++t) {
    const int cur = t & 1;
    bf16x8 kr, vr;
    if (t < 35) {  // issue next-tile global loads early (hide under compute)
      kr = *reinterpret_cast<const bf16x8*>(kg + (t + 1) * (64 * HD));
      vr = *reinterpret_cast<const bf16x8*>(vg + (t + 1) * 64);
    }
    const bf16* kc = smem.kv.k[cur];
    const bf16* vc = smem.kv.v[cur];

    // S^T = K . Q^T over this wave's 32-j subtile
    f32x16 s = {};
    __builtin_amdgcn_s_setprio(1);
#pragma unroll
    for (int kk = 0; kk < 4; ++kk) {
      bf16x8 kf = *reinterpret_cast<const bf16x8*>(kc + ksw[kk]);
      s = MFMA32(kf, q[kk], s);
    }
    __builtin_amdgcn_s_setprio(0);

    // zero-max softmax: P = 2^s (raw v_exp_f32), lane-local partial sum
    u32 P[8];
    float la = 0.f, lb = 0.f;
#pragma unroll
    for (int m = 0; m < 8; ++m) {
      float e0 = fexp2(s[2 * m]);
      float e1 = fexp2(s[2 * m + 1]);
      la += e0;
      lb += e1;
      u32 pk;
      asm("v_cvt_pk_bf16_f32 %0, %1, %2" : "=v"(pk) : "v"(e0), "v"(e1));
      P[m] = pk;
    }
    l_r += la + lb;

    // PV: build B-frags in regs via permlane32_swap, accumulate O^T
#pragma unroll
    for (int J = 0; J < 2; ++J) {
      u32 w0 = P[4 * J], w2 = P[4 * J + 2];
      asm("v_permlane32_swap_b32 %0, %1" : "+v"(w0), "+v"(w2));
      u32 w1 = P[4 * J + 1], w3 = P[4 * J + 3];
      asm("v_permlane32_swap_b32 %0, %1" : "+v"(w1), "+v"(w3));
      i32x4 wv;
      wv[0] = (int)w0; wv[1] = (int)w1; wv[2] = (int)w2; wv[3] = (int)w3;
      bf16x8 pf = __builtin_bit_cast(bf16x8, wv);
      bf16x8 v0 = *reinterpret_cast<const bf16x8*>(vc + vsw0[J]);
      bf16x8 v1 = *reinterpret_cast<const bf16x8*>(vc + vsw1[J]);
      __builtin_amdgcn_s_setprio(1);
      acc0 = MFMA32(v0, pf, acc0);
      acc1 = MFMA32(v1, pf, acc1);
      __builtin_amdgcn_s_setprio(0);
    }

    if (t < 35) {  // write staged regs into other buffer
      const int nb = cur ^ 1;
      *reinterpret_cast<bf16x8*>(&smem.kv.k[nb][lw]) = kr;
      *reinterpret_cast<bf16x8*>(&smem.kv.v[nb][lw]) = vr;
    }
    asm volatile("s_waitcnt lgkmcnt(0)" ::: "memory");
    __builtin_amdgcn_s_barrier();
  }

  // merge jsub halves (plain add, zero-max => no rescale), two phases
  if (jsub == 1) {
    float* mb = smem.m[ig][lane];
#pragma unroll
    for (int e = 0; e < 16; ++e) mb[e] = acc0[e];
    mb[16] = l_r;
  }
  __syncthreads();
  if (jsub == 0) {
    const float* mb = smem.m[ig][lane];
#pragma unroll
    for (int e = 0; e < 16; ++e) acc0[e] += mb[e];
    l_r += mb[16];
  }
  __syncthreads();
  if (jsub == 1) {
    float* mb = smem.m[ig][lane];
#pragma unroll
    for (int e = 0; e < 16; ++e) mb[e] = acc1[e];
  }
  __syncthreads();
  if (jsub == 0) {
    const float* mb = smem.m[ig][lane];
#pragma unroll
    for (int e = 0; e < 16; ++e) acc1[e] += mb[e];
    l_r += __shfl_xor(l_r, 32);
    const float inv = 1.0f / l_r;
    bf16* ob = att + ((size_t)(b * NHW) + i0w + l31) * NC + n * HD;
#pragma unroll
    for (int rq = 0; rq < 4; ++rq) {
      bf16x4 o0, o1;
#pragma unroll
      for (int c = 0; c < 4; ++c) {
        o0[c] = (bf16)(acc0[rq * 4 + c] * inv);
        o1[c] = (bf16)(acc1[rq * 4 + c] * inv);
      }
      *reinterpret_cast<bf16x4*>(ob + 8 * rq + 4 * g2) = o0;
      *reinterpret_cast<bf16x4*>(ob + 32 + 8 * rq + 4 * g2) = o1;
    }
  }
}

// ---------------- proj GEMM + bias + residual ----------------
__global__ __launch_bounds__(256) void k_proj(const bf16* __restrict__ att,
                                              const bf16* __restrict__ wp,
                                              const float* __restrict__ pb,
                                              const float* __restrict__ x,
                                              float* __restrict__ out) {
  int b = blockIdx.z;
  int i_base = blockIdx.x * 128;
  int o_base = blockIdx.y * 128;
  int t = threadIdx.x;
  int lane = t & 63, wid = t >> 6;
  int wm = (wid >> 1) * 64, wn = (wid & 1) * 64;
  int l15 = lane & 15, g = lane >> 4;
  const bf16* ab = wp + (o_base + wm + l15) * NC + g * 8;
  const bf16* bb = att + (b * NHW + i_base + wn + l15) * NC + g * 8;
  f32x4 acc[4][4] = {};
#pragma unroll 2
  for (int kc = 0; kc < 8; ++kc) {
    bf16x8 af[4], bf[4];
#pragma unroll
    for (int mf = 0; mf < 4; ++mf)
      af[mf] = *reinterpret_cast<const bf16x8*>(ab + mf * 16 * NC + kc * 32);
#pragma unroll
    for (int nf = 0; nf < 4; ++nf)
      bf[nf] = *reinterpret_cast<const bf16x8*>(bb + nf * 16 * NC + kc * 32);
#pragma unroll
    for (int mf = 0; mf < 4; ++mf)
#pragma unroll
      for (int nf = 0; nf < 4; ++nf)
        acc[mf][nf] = MFMA16(af[mf], bf[nf], acc[mf][nf]);
  }
  int orow0 = o_base + wm + g * 4;
#pragma unroll
  for (int mf = 0; mf < 4; ++mf)
#pragma unroll
    for (int r = 0; r < 4; ++r) {
      int o = orow0 + mf * 16 + r;
      float bias = pb[o];
      const float* xr = x + (b * NC + o) * NHW + i_base + wn;
      float* orow = out + (b * NC + o) * NHW + i_base + wn;
#pragma unroll
      for (int nf = 0; nf < 4; ++nf) {
        int i = nf * 16 + l15;
        orow[i] = acc[mf][nf][r] + bias + xr[i];
      }
    }
}

extern "C" void kernel_launch(void* const* d_in, const int* in_sizes, int n_in,
                              void* d_out, int out_size, void* d_ws, size_t ws_size,
                              hipStream_t stream) {
  const float* x    = (const float*)d_in[0];
  const float* gnw  = (const float*)d_in[1];
  const float* gnb  = (const float*)d_in[2];
  const float* qkvw = (const float*)d_in[3];
  const float* qkvb = (const float*)d_in[4];
  const float* pw   = (const float*)d_in[5];
  const float* pb   = (const float*)d_in[6];
  float* out = (float*)d_out;

  bf16* ws = (bf16*)d_ws;
  const size_t NE = (size_t)NB * NHW * NC;
  bf16* xnt = ws;
  bf16* qt  = ws + NE;
  bf16* kt  = ws + 2 * NE;
  bf16* vv  = ws + 3 * NE;
  bf16* att = ws + 4 * NE;
  bf16* wqb = ws + 5 * NE;
  bf16* wpb = wqb + 768 * 256;

  k_pre<<<1024, 256, 0, stream>>>(x, gnw, gnb, qkvw, pw, xnt, wqb, wpb);
  k_qkv<<<dim3(18, 6, NB), 256, 0, stream>>>(xnt, wqb, qkvb, qt, kt, vv);
  k_attn<<<576, 512, 0, stream>>>(qt, kt, vv, att);
  k_proj<<<dim3(18, 2, NB), 256, 0, stream>>>(att, wpb, pb, x, out);
}

// Round 18
// 140.142 us; speedup vs baseline: 1.5568x; 1.0266x over previous
//
#include <hip/hip_runtime.h>
#include <hip/hip_bf16.h>
#include <math.h>

#define NB 8
#define NC 256
#define NHW 2304
#define NH 4
#define HD 64
#define CPG 8
#define GN_EPS 1e-5f

typedef __bf16 bf16;
typedef __bf16 bf16x4 __attribute__((ext_vector_type(4)));
typedef __bf16 bf16x8 __attribute__((ext_vector_type(8)));
typedef float f32x4 __attribute__((ext_vector_type(4)));
typedef float f32x16 __attribute__((ext_vector_type(16)));
typedef int i32x4 __attribute__((ext_vector_type(4)));
typedef unsigned int u32;

#define MFMA16(a, b, c) __builtin_amdgcn_mfma_f32_16x16x32_bf16(a, b, c, 0, 0, 0)
#define MFMA32(a, b, c) __builtin_amdgcn_mfma_f32_32x32x16_bf16(a, b, c, 0, 0, 0)

// fast 2^x: raw v_exp_f32 (exact for our |x| <~ 40 range)
__device__ __forceinline__ float fexp2(float x) {
  float r;
  asm("v_exp_f32 %0, %1" : "=v"(r) : "v"(x));
  return r;
}

// ---------------- fused: weight fp32->bf16 (blocks 0..767) + GroupNorm ------
__global__ __launch_bounds__(256) void k_pre(const float* __restrict__ x,
                                             const float* __restrict__ gw,
                                             const float* __restrict__ gb,
                                             const float* __restrict__ qw,
                                             const float* __restrict__ pw,
                                             bf16* __restrict__ xnt,
                                             bf16* __restrict__ wq,
                                             bf16* __restrict__ wp) {
  int t = threadIdx.x;
  if (blockIdx.x < 768) {
    int i = blockIdx.x * 256 + t;
    wq[i] = (bf16)qw[i];
    if (i < NC * NC) wp[i] = (bf16)pw[i];
    return;
  }
  int bid = blockIdx.x - 768;
  int b = bid >> 5;
  int g = bid & 31;
  int c0 = g * CPG;
  const float* xb = x + (b * NC + c0) * NHW;
  float v[CPG][9];
  float s = 0.f, s2 = 0.f;
#pragma unroll
  for (int cc = 0; cc < CPG; ++cc)
#pragma unroll
    for (int k = 0; k < 9; ++k) {
      float val = xb[cc * NHW + k * 256 + t];
      v[cc][k] = val;
      s += val;
      s2 += val * val;
    }
#pragma unroll
  for (int m = 1; m < 64; m <<= 1) {
    s += __shfl_xor(s, m);
    s2 += __shfl_xor(s2, m);
  }
  __shared__ float red[8];
  int wid = t >> 6;
  if ((t & 63) == 0) { red[wid] = s; red[4 + wid] = s2; }
  __syncthreads();
  s = red[0] + red[1] + red[2] + red[3];
  s2 = red[4] + red[5] + red[6] + red[7];
  const float inv_n = 1.0f / (CPG * NHW);
  float mean = s * inv_n;
  float var = s2 * inv_n - mean * mean;
  float rsq = rsqrtf(var + GN_EPS);
  float ka[CPG], kb[CPG];
#pragma unroll
  for (int cc = 0; cc < CPG; ++cc) {
    float wv = gw[c0 + cc];
    ka[cc] = wv * rsq;
    kb[cc] = gb[c0 + cc] - mean * rsq * wv;
  }
  bf16* dst = xnt + b * NHW * NC + c0;
#pragma unroll
  for (int k = 0; k < 9; ++k) {
    bf16x8 o;
#pragma unroll
    for (int cc = 0; cc < CPG; ++cc)
      o[cc] = (bf16)(v[cc][k] * ka[cc] + kb[cc]);
    *reinterpret_cast<bf16x8*>(dst + (k * 256 + t) * NC) = o;
  }
}

// ---------------- QKV GEMM: M=hw(i), N=768(o), K=256(c) ----------------
// NEW: per-wave LDS transpose epilogue — Q/K stores become 64B-contiguous
// segments, V stores become 128B row segments (was scattered 8B stores at
// 128B / 4608B stride). Tile 4.6KB/wave (18.4KB/block), two o-halves, all
// hazards same-wave (compiler lgkmcnt, no barriers).
__global__ __launch_bounds__(256) void k_qkv(const bf16* __restrict__ xnt,
                                             const bf16* __restrict__ wq,
                                             const float* __restrict__ qkvb,
                                             bf16* __restrict__ qt,
                                             bf16* __restrict__ kt,
                                             bf16* __restrict__ vv) {
  __shared__ bf16 tbuf[4][2304];  // 4.5KB per wave
  int b = blockIdx.z;
  int i_base = blockIdx.x * 128;
  int o_base = blockIdx.y * 128;
  int t = threadIdx.x;
  int lane = t & 63, wid = t >> 6;
  int wm = (wid >> 1) * 64, wn = (wid & 1) * 64;
  int l15 = lane & 15, g = lane >> 4;
  const bool qk = (o_base < 512);
  const bf16* ab;
  const bf16* bb;
  if (qk) {
    ab = wq + (o_base + wm + l15) * NC + g * 8;
    bb = xnt + ((size_t)b * NHW + i_base + wn + l15) * NC + g * 8;
  } else {
    ab = xnt + ((size_t)b * NHW + i_base + wm + l15) * NC + g * 8;
    bb = wq + (o_base + wn + l15) * NC + g * 8;
  }
  f32x4 acc[4][4] = {};
#pragma unroll 2
  for (int kc = 0; kc < 8; ++kc) {
    bf16x8 af[4], bf[4];
#pragma unroll
    for (int mf = 0; mf < 4; ++mf)
      af[mf] = *reinterpret_cast<const bf16x8*>(ab + mf * 16 * NC + kc * 32);
#pragma unroll
    for (int nf = 0; nf < 4; ++nf)
      bf[nf] = *reinterpret_cast<const bf16x8*>(bb + nf * 16 * NC + kc * 32);
#pragma unroll
    for (int mf = 0; mf < 4; ++mf)
#pragma unroll
      for (int nf = 0; nf < 4; ++nf)
        acc[mf][nf] = MFMA16(af[mf], bf[nf], acc[mf][nf]);
  }
  bf16* T = tbuf[wid];
  if (qk) {
    // D[row=o][col=i]; wave o-slab o0w (64-aligned) -> one 64-hd dst slab
    const float qscale = 0.125f * 1.4426950408889634f;
    int o0w = o_base + wm;
    bool isQ = (o0w < 256);
    float sc = isQ ? qscale : 1.0f;
    int oo = isQ ? o0w : o0w - 256;
    bf16* dstb = (isQ ? qt : kt) +
                 ((size_t)(b * NH + (oo >> 6)) * NHW + i_base + wn) * HD;
#pragma unroll
    for (int h = 0; h < 2; ++h) {
      // write half: tile [64 i][36 (32 o + pad)]
#pragma unroll
      for (int mfh = 0; mfh < 2; ++mfh) {
        int mf = 2 * h + mfh;
        int o_l = mf * 16 + g * 4;  // 4 consec via r
        f32x4 b4 = *reinterpret_cast<const f32x4*>(qkvb + o0w + o_l);
#pragma unroll
        for (int nf = 0; nf < 4; ++nf) {
          int i_l = nf * 16 + l15;
          bf16x4 w;
#pragma unroll
          for (int r = 0; r < 4; ++r)
            w[r] = (bf16)((acc[mf][nf][r] + b4[r]) * sc);
          *reinterpret_cast<bf16x4*>(&T[i_l * 36 + (o_l - h * 32)]) = w;
        }
      }
      // read + coalesced store: 16 i x 64B segments per instr
#pragma unroll
      for (int u = 0; u < 4; ++u) {
        int i_l = u * 16 + (lane >> 2);
        int ch = (lane & 3) * 8;
        bf16x8 w = *reinterpret_cast<const bf16x8*>(&T[i_l * 36 + ch]);
        *reinterpret_cast<bf16x8*>(dstb + (size_t)i_l * HD + h * 32 + ch) = w;
      }
    }
  } else {
    // D[row=i][col=o]; wave o-slab (o_base+wn, 64-aligned) -> vv rows
    int ovw = o_base + wn - 512;  // 0..255, 64-aligned
    bf16* vdst = vv + ((size_t)(b * NH + (ovw >> 6)) * HD) * NHW + i_base + wm;
#pragma unroll
    for (int h = 0; h < 2; ++h) {
      // write half: tile [32 o][72 (64 i + pad)]
#pragma unroll
      for (int nfh = 0; nfh < 2; ++nfh) {
        int nf = 2 * h + nfh;
        int o_l = nf * 16 + l15 - h * 32;  // 0..31
        float bias = qkvb[512 + ovw + h * 32 + o_l];
#pragma unroll
        for (int mf = 0; mf < 4; ++mf) {
          int i_l0 = mf * 16 + g * 4;
          bf16x4 w;
#pragma unroll
          for (int r = 0; r < 4; ++r) w[r] = (bf16)(acc[mf][nf][r] + bias);
          *reinterpret_cast<bf16x4*>(&T[o_l * 72 + i_l0]) = w;
        }
      }
      // read + coalesced store: 8 o-rows x 128B contiguous per instr
#pragma unroll
      for (int u = 0; u < 4; ++u) {
        int o_r = u * 8 + (lane >> 3);
        int ch = (lane & 7) * 8;
        bf16x8 w = *reinterpret_cast<const bf16x8*>(&T[o_r * 72 + ch]);
        *reinterpret_cast<bf16x8*>(vdst + (size_t)(h * 32 + o_r) * NHW + ch) = w;
      }
    }
  }
}

// ---------------- flash attention: r13 (best measured: 78.4us) --------------
// 512 thr, 8 waves = (ig 0..3, jsub 0..1), 128i x 64j tiles, 32KB LDS dbuf,
// chunk-major rotated layout elem(c,row) = c*512 + ((row+c)&63)*8, zero-max
// fexp2 softmax, permlane P->B-frags, one lgkm+barrier per tile. Grid 576 =
// 8 XCD x 72 (bijective swizzle, 4 heads/XCD L2-resident).
__global__ __launch_bounds__(512, 4) void k_attn(const bf16* __restrict__ qt,
                                                 const bf16* __restrict__ kt,
                                                 const bf16* __restrict__ vv,
                                                 bf16* __restrict__ att) {
  __shared__ union SM {
    struct { bf16 k[2][4096]; bf16 v[2][4096]; } kv;  // 32 KB
    float m[4][64][17];                                // 17.4 KB (epilogue)
  } smem;

  const int tid = threadIdx.x;
  const int wid = tid >> 6, lane = tid & 63;
  const int l31 = lane & 31, g2 = lane >> 5;
  const int ig = wid & 3, jsub = wid >> 2;

  // bijective XCD swizzle: 576 blocks = 8 XCD x 72; each XCD gets 4 heads
  const int bid = blockIdx.x;
  const int wg = (bid & 7) * 72 + (bid >> 3);
  const int bh = wg / 18, it = wg % 18;
  const int b = bh >> 2, n = bh & 3;
  const int i0w = it * 128 + ig * 32;

  const bf16* qb = qt + (size_t)bh * NHW * HD;
  const bf16* kb = kt + (size_t)bh * NHW * HD;
  const bf16* vb = vv + (size_t)bh * HD * NHW;

  // staging: 512 thr -> (r0 = row 0..63, cs = chunk 0..7), 1 K + 1 V chunk
  const int r0 = tid >> 3, cs = tid & 7;
  const bf16* kg = kb + r0 * HD + cs * 8;
  const bf16* vg = vb + (size_t)r0 * NHW + cs * 8;
#define EOFF(c, row) ((c) * 512 + ((((row) + (c)) & 63) << 3))
  const int lw = EOFF(cs, r0);

  // K fragment offsets: chunk 2kk+g2, rows jsub*32 + l31 (contiguous 512B)
  int ksw[4];
#pragma unroll
  for (int kk = 0; kk < 4; ++kk) ksw[kk] = EOFF(2 * kk + g2, jsub * 32 + l31);
  // V fragment offsets: chunk jsub*4+J*2+g2, rows l31 / l31+32
  int vsw0[2], vsw1[2];
#pragma unroll
  for (int J = 0; J < 2; ++J) {
    int c = jsub * 4 + J * 2 + g2;
    vsw0[J] = EOFF(c, l31);
    vsw1[J] = EOFF(c, l31 + 32);
  }
#undef EOFF

  // Q fragments: B-frag col i=l31, d = 16*kk + 8*g2 + e
  bf16x8 q[4];
#pragma unroll
  for (int kk = 0; kk < 4; ++kk)
    q[kk] = *reinterpret_cast<const bf16x8*>(qb + (i0w + l31) * HD + kk * 16 + g2 * 8);

  f32x16 acc0 = {}, acc1 = {};
  float l_r = 0.f;

  // prologue: stage tile 0 into buf 0
  {
    bf16x8 a = *reinterpret_cast<const bf16x8*>(kg);
    bf16x8 d = *reinterpret_cast<const bf16x8*>(vg);
    *reinterpret_cast<bf16x8*>(&smem.kv.k[0][lw]) = a;
    *reinterpret_cast<bf16x8*>(&smem.kv.v[0][lw]) = d;
  }
  asm volatile("s_waitcnt lgkmcnt(0)" ::: "memory");
  __builtin_amdgcn_s_barrier();

  for (int t = 0; t < 36; ++t) {
    const int cur = t & 1;
    bf16x8 kr, vr;
    if (t < 35) {  // issue next-tile global loads early (hide under compute)
      kr = *reinterpret_cast<const bf16x8*>(kg + (t + 1) * (64 * HD));
      vr = *reinterpret_cast<const bf16x8*>(vg + (t + 1) * 64);
    }
    const bf16* kc = smem.kv.k[cur];
    const bf16* vc = smem.kv.v[cur];

    // S^T = K . Q^T over this wave's 32-j subtile
    f32x16 s = {};
    __builtin_amdgcn_s_setprio(1);
#pragma unroll
    for (int kk = 0; kk < 4; ++kk) {
      bf16x8 kf = *reinterpret_cast<const bf16x8*>(kc + ksw[kk]);
      s = MFMA32(kf, q[kk], s);
    }
    __builtin_amdgcn_s_setprio(0);

    // zero-max softmax: P = 2^s (raw v_exp_f32), lane-local partial sum
    u32 P[8];
    float la = 0.f, lb = 0.f;
#pragma unroll
    for (int m = 0; m < 8; ++m) {
      float e0 = fexp2(s[2 * m]);
      float e1 = fexp2(s[2 * m + 1]);
      la += e0;
      lb += e1;
      u32 pk;
      asm("v_cvt_pk_bf16_f32 %0, %1, %2" : "=v"(pk) : "v"(e0), "v"(e1));
      P[m] = pk;
    }
    l_r += la + lb;

    // PV: build B-frags in regs via permlane32_swap, accumulate O^T
#pragma unroll
    for (int J = 0; J < 2; ++J) {
      u32 w0 = P[4 * J], w2 = P[4 * J + 2];
      asm("v_permlane32_swap_b32 %0, %1" : "+v"(w0), "+v"(w2));
      u32 w1 = P[4 * J + 1], w3 = P[4 * J + 3];
      asm("v_permlane32_swap_b32 %0, %1" : "+v"(w1), "+v"(w3));
      i32x4 wv;
      wv[0] = (int)w0; wv[1] = (int)w1; wv[2] = (int)w2; wv[3] = (int)w3;
      bf16x8 pf = __builtin_bit_cast(bf16x8, wv);
      bf16x8 v0 = *reinterpret_cast<const bf16x8*>(vc + vsw0[J]);
      bf16x8 v1 = *reinterpret_cast<const bf16x8*>(vc + vsw1[J]);
      __builtin_amdgcn_s_setprio(1);
      acc0 = MFMA32(v0, pf, acc0);
      acc1 = MFMA32(v1, pf, acc1);
      __builtin_amdgcn_s_setprio(0);
    }

    if (t < 35) {  // write staged regs into other buffer
      const int nb = cur ^ 1;
      *reinterpret_cast<bf16x8*>(&smem.kv.k[nb][lw]) = kr;
      *reinterpret_cast<bf16x8*>(&smem.kv.v[nb][lw]) = vr;
    }
    asm volatile("s_waitcnt lgkmcnt(0)" ::: "memory");
    __builtin_amdgcn_s_barrier();
  }

  // merge jsub halves (plain add, zero-max => no rescale), two phases
  if (jsub == 1) {
    float* mb = smem.m[ig][lane];
#pragma unroll
    for (int e = 0; e < 16; ++e) mb[e] = acc0[e];
    mb[16] = l_r;
  }
  __syncthreads();
  if (jsub == 0) {
    const float* mb = smem.m[ig][lane];
#pragma unroll
    for (int e = 0; e < 16; ++e) acc0[e] += mb[e];
    l_r += mb[16];
  }
  __syncthreads();
  if (jsub == 1) {
    float* mb = smem.m[ig][lane];
#pragma unroll
    for (int e = 0; e < 16; ++e) mb[e] = acc1[e];
  }
  __syncthreads();
  if (jsub == 0) {
    const float* mb = smem.m[ig][lane];
#pragma unroll
    for (int e = 0; e < 16; ++e) acc1[e] += mb[e];
    l_r += __shfl_xor(l_r, 32);
    const float inv = 1.0f / l_r;
    bf16* ob = att + ((size_t)(b * NHW) + i0w + l31) * NC + n * HD;
#pragma unroll
    for (int rq = 0; rq < 4; ++rq) {
      bf16x4 o0, o1;
#pragma unroll
      for (int c = 0; c < 4; ++c) {
        o0[c] = (bf16)(acc0[rq * 4 + c] * inv);
        o1[c] = (bf16)(acc1[rq * 4 + c] * inv);
      }
      *reinterpret_cast<bf16x4*>(ob + 8 * rq + 4 * g2) = o0;
      *reinterpret_cast<bf16x4*>(ob + 32 + 8 * rq + 4 * g2) = o1;
    }
  }
}

// ---------------- proj GEMM + bias + residual ----------------
__global__ __launch_bounds__(256) void k_proj(const bf16* __restrict__ att,
                                              const bf16* __restrict__ wp,
                                              const float* __restrict__ pb,
                                              const float* __restrict__ x,
                                              float* __restrict__ out) {
  int b = blockIdx.z;
  int i_base = blockIdx.x * 128;
  int o_base = blockIdx.y * 128;
  int t = threadIdx.x;
  int lane = t & 63, wid = t >> 6;
  int wm = (wid >> 1) * 64, wn = (wid & 1) * 64;
  int l15 = lane & 15, g = lane >> 4;
  const bf16* ab = wp + (o_base + wm + l15) * NC + g * 8;
  const bf16* bb = att + (b * NHW + i_base + wn + l15) * NC + g * 8;
  f32x4 acc[4][4] = {};
#pragma unroll 2
  for (int kc = 0; kc < 8; ++kc) {
    bf16x8 af[4], bf[4];
#pragma unroll
    for (int mf = 0; mf < 4; ++mf)
      af[mf] = *reinterpret_cast<const bf16x8*>(ab + mf * 16 * NC + kc * 32);
#pragma unroll
    for (int nf = 0; nf < 4; ++nf)
      bf[nf] = *reinterpret_cast<const bf16x8*>(bb + nf * 16 * NC + kc * 32);
#pragma unroll
    for (int mf = 0; mf < 4; ++mf)
#pragma unroll
      for (int nf = 0; nf < 4; ++nf)
        acc[mf][nf] = MFMA16(af[mf], bf[nf], acc[mf][nf]);
  }
  int orow0 = o_base + wm + g * 4;
#pragma unroll
  for (int mf = 0; mf < 4; ++mf)
#pragma unroll
    for (int r = 0; r < 4; ++r) {
      int o = orow0 + mf * 16 + r;
      float bias = pb[o];
      const float* xr = x + (b * NC + o) * NHW + i_base + wn;
      float* orow = out + (b * NC + o) * NHW + i_base + wn;
#pragma unroll
      for (int nf = 0; nf < 4; ++nf) {
        int i = nf * 16 + l15;
        orow[i] = acc[mf][nf][r] + bias + xr[i];
      }
    }
}

extern "C" void kernel_launch(void* const* d_in, const int* in_sizes, int n_in,
                              void* d_out, int out_size, void* d_ws, size_t ws_size,
                              hipStream_t stream) {
  const float* x    = (const float*)d_in[0];
  const float* gnw  = (const float*)d_in[1];
  const float* gnb  = (const float*)d_in[2];
  const float* qkvw = (const float*)d_in[3];
  const float* qkvb = (const float*)d_in[4];
  const float* pw   = (const float*)d_in[5];
  const float* pb   = (const float*)d_in[6];
  float* out = (float*)d_out;

  bf16* ws = (bf16*)d_ws;
  const size_t NE = (size_t)NB * NHW * NC;
  bf16* xnt = ws;
  bf16* qt  = ws + NE;
  bf16* kt  = ws + 2 * NE;
  bf16* vv  = ws + 3 * NE;
  bf16* att = ws + 4 * NE;
  bf16* wqb = ws + 5 * NE;
  bf16* wpb = wqb + 768 * 256;

  k_pre<<<1024, 256, 0, stream>>>(x, gnw, gnb, qkvw, pw, xnt, wqb, wpb);
  k_qkv<<<dim3(18, 6, NB), 256, 0, stream>>>(xnt, wqb, qkvb, qt, kt, vv);
  k_attn<<<576, 512, 0, stream>>>(qt, kt, vv, att);
  k_proj<<<dim3(18, 2, NB), 256, 0, stream>>>(att, wpb, pb, x, out);
}

// Round 19
// 139.945 us; speedup vs baseline: 1.5590x; 1.0014x over previous
//
#include <hip/hip_runtime.h>
#include <hip/hip_bf16.h>
#include <math.h>

#define NB 8
#define NC 256
#define NHW 2304
#define NH 4
#define HD 64
#define CPG 8
#define GN_EPS 1e-5f

typedef __bf16 bf16;
typedef __bf16 bf16x4 __attribute__((ext_vector_type(4)));
typedef __bf16 bf16x8 __attribute__((ext_vector_type(8)));
typedef float f32x4 __attribute__((ext_vector_type(4)));
typedef float f32x16 __attribute__((ext_vector_type(16)));
typedef int i32x4 __attribute__((ext_vector_type(4)));
typedef unsigned int u32;

#define MFMA16(a, b, c) __builtin_amdgcn_mfma_f32_16x16x32_bf16(a, b, c, 0, 0, 0)
#define MFMA32(a, b, c) __builtin_amdgcn_mfma_f32_32x32x16_bf16(a, b, c, 0, 0, 0)

// fast 2^x: raw v_exp_f32 (exact for our |x| <~ 40 range)
__device__ __forceinline__ float fexp2(float x) {
  float r;
  asm("v_exp_f32 %0, %1" : "=v"(r) : "v"(x));
  return r;
}

// ---------------- fused: weight fp32->bf16 (blocks 0..255) + GroupNorm ------
// GN with 768-thr blocks (12 waves): 512 total blocks ~ 2/CU ~ 24 waves/CU
// (was 4 waves/CU) — memory-bound pass now has latency-hiding TLP.
// Single-pass: thread holds 8ch x 3pos slice (24 f32) in regs, x read ONCE.
__global__ __launch_bounds__(768) void k_pre(const float* __restrict__ x,
                                             const float* __restrict__ gw,
                                             const float* __restrict__ gb,
                                             const float* __restrict__ qw,
                                             const float* __restrict__ pw,
                                             bf16* __restrict__ xnt,
                                             bf16* __restrict__ wq,
                                             bf16* __restrict__ wp) {
  int t = threadIdx.x;
  if (blockIdx.x < 256) {
    int i = blockIdx.x * 768 + t;  // 256*768 = 196608 = 768*256 exactly
    wq[i] = (bf16)qw[i];
    if (i < NC * NC) wp[i] = (bf16)pw[i];
    return;
  }
  int bid = blockIdx.x - 256;
  int b = bid >> 5;
  int g = bid & 31;
  int c0 = g * CPG;
  const float* xb = x + (b * NC + c0) * NHW;
  float v[CPG][3];
  float s = 0.f, s2 = 0.f;
#pragma unroll
  for (int cc = 0; cc < CPG; ++cc)
#pragma unroll
    for (int k = 0; k < 3; ++k) {
      float val = xb[cc * NHW + k * 768 + t];
      v[cc][k] = val;
      s += val;
      s2 += val * val;
    }
#pragma unroll
  for (int m = 1; m < 64; m <<= 1) {
    s += __shfl_xor(s, m);
    s2 += __shfl_xor(s2, m);
  }
  __shared__ float red[24];
  int wid = t >> 6;
  if ((t & 63) == 0) { red[wid] = s; red[12 + wid] = s2; }
  __syncthreads();
  s = 0.f; s2 = 0.f;
#pragma unroll
  for (int w = 0; w < 12; ++w) { s += red[w]; s2 += red[12 + w]; }
  const float inv_n = 1.0f / (CPG * NHW);
  float mean = s * inv_n;
  float var = s2 * inv_n - mean * mean;
  float rsq = rsqrtf(var + GN_EPS);
  float ka[CPG], kb[CPG];
#pragma unroll
  for (int cc = 0; cc < CPG; ++cc) {
    float wv = gw[c0 + cc];
    ka[cc] = wv * rsq;
    kb[cc] = gb[c0 + cc] - mean * rsq * wv;
  }
  bf16* dst = xnt + b * NHW * NC + c0;
#pragma unroll
  for (int k = 0; k < 3; ++k) {
    bf16x8 o;
#pragma unroll
    for (int cc = 0; cc < CPG; ++cc)
      o[cc] = (bf16)(v[cc][k] * ka[cc] + kb[cc]);
    *reinterpret_cast<bf16x8*>(dst + (k * 768 + t) * NC) = o;
  }
}

// ---------------- QKV GEMM: M=hw(i), N=768(o), K=256(c) ----------------
// Per-wave LDS transpose epilogue — Q/K stores become 64B-contiguous
// segments, V stores become 128B row segments. Tile 4.5KB/wave, two
// o-halves, all hazards same-wave (compiler lgkmcnt, no barriers).
__global__ __launch_bounds__(256) void k_qkv(const bf16* __restrict__ xnt,
                                             const bf16* __restrict__ wq,
                                             const float* __restrict__ qkvb,
                                             bf16* __restrict__ qt,
                                             bf16* __restrict__ kt,
                                             bf16* __restrict__ vv) {
  __shared__ bf16 tbuf[4][2304];  // 4.5KB per wave
  int b = blockIdx.z;
  int i_base = blockIdx.x * 128;
  int o_base = blockIdx.y * 128;
  int t = threadIdx.x;
  int lane = t & 63, wid = t >> 6;
  int wm = (wid >> 1) * 64, wn = (wid & 1) * 64;
  int l15 = lane & 15, g = lane >> 4;
  const bool qk = (o_base < 512);
  const bf16* ab;
  const bf16* bb;
  if (qk) {
    ab = wq + (o_base + wm + l15) * NC + g * 8;
    bb = xnt + ((size_t)b * NHW + i_base + wn + l15) * NC + g * 8;
  } else {
    ab = xnt + ((size_t)b * NHW + i_base + wm + l15) * NC + g * 8;
    bb = wq + (o_base + wn + l15) * NC + g * 8;
  }
  f32x4 acc[4][4] = {};
#pragma unroll 2
  for (int kc = 0; kc < 8; ++kc) {
    bf16x8 af[4], bf[4];
#pragma unroll
    for (int mf = 0; mf < 4; ++mf)
      af[mf] = *reinterpret_cast<const bf16x8*>(ab + mf * 16 * NC + kc * 32);
#pragma unroll
    for (int nf = 0; nf < 4; ++nf)
      bf[nf] = *reinterpret_cast<const bf16x8*>(bb + nf * 16 * NC + kc * 32);
#pragma unroll
    for (int mf = 0; mf < 4; ++mf)
#pragma unroll
      for (int nf = 0; nf < 4; ++nf)
        acc[mf][nf] = MFMA16(af[mf], bf[nf], acc[mf][nf]);
  }
  bf16* T = tbuf[wid];
  if (qk) {
    const float qscale = 0.125f * 1.4426950408889634f;
    int o0w = o_base + wm;
    bool isQ = (o0w < 256);
    float sc = isQ ? qscale : 1.0f;
    int oo = isQ ? o0w : o0w - 256;
    bf16* dstb = (isQ ? qt : kt) +
                 ((size_t)(b * NH + (oo >> 6)) * NHW + i_base + wn) * HD;
#pragma unroll
    for (int h = 0; h < 2; ++h) {
#pragma unroll
      for (int mfh = 0; mfh < 2; ++mfh) {
        int mf = 2 * h + mfh;
        int o_l = mf * 16 + g * 4;
        f32x4 b4 = *reinterpret_cast<const f32x4*>(qkvb + o0w + o_l);
#pragma unroll
        for (int nf = 0; nf < 4; ++nf) {
          int i_l = nf * 16 + l15;
          bf16x4 w;
#pragma unroll
          for (int r = 0; r < 4; ++r)
            w[r] = (bf16)((acc[mf][nf][r] + b4[r]) * sc);
          *reinterpret_cast<bf16x4*>(&T[i_l * 36 + (o_l - h * 32)]) = w;
        }
      }
#pragma unroll
      for (int u = 0; u < 4; ++u) {
        int i_l = u * 16 + (lane >> 2);
        int ch = (lane & 3) * 8;
        bf16x8 w = *reinterpret_cast<const bf16x8*>(&T[i_l * 36 + ch]);
        *reinterpret_cast<bf16x8*>(dstb + (size_t)i_l * HD + h * 32 + ch) = w;
      }
    }
  } else {
    int ovw = o_base + wn - 512;
    bf16* vdst = vv + ((size_t)(b * NH + (ovw >> 6)) * HD) * NHW + i_base + wm;
#pragma unroll
    for (int h = 0; h < 2; ++h) {
#pragma unroll
      for (int nfh = 0; nfh < 2; ++nfh) {
        int nf = 2 * h + nfh;
        int o_l = nf * 16 + l15 - h * 32;
        float bias = qkvb[512 + ovw + h * 32 + o_l];
#pragma unroll
        for (int mf = 0; mf < 4; ++mf) {
          int i_l0 = mf * 16 + g * 4;
          bf16x4 w;
#pragma unroll
          for (int r = 0; r < 4; ++r) w[r] = (bf16)(acc[mf][nf][r] + bias);
          *reinterpret_cast<bf16x4*>(&T[o_l * 72 + i_l0]) = w;
        }
      }
#pragma unroll
      for (int u = 0; u < 4; ++u) {
        int o_r = u * 8 + (lane >> 3);
        int ch = (lane & 7) * 8;
        bf16x8 w = *reinterpret_cast<const bf16x8*>(&T[o_r * 72 + ch]);
        *reinterpret_cast<bf16x8*>(vdst + (size_t)(h * 32 + o_r) * NHW + ch) = w;
      }
    }
  }
}

// ---------------- flash attention: r13 (best measured: 78.4us) --------------
__global__ __launch_bounds__(512, 4) void k_attn(const bf16* __restrict__ qt,
                                                 const bf16* __restrict__ kt,
                                                 const bf16* __restrict__ vv,
                                                 bf16* __restrict__ att) {
  __shared__ union SM {
    struct { bf16 k[2][4096]; bf16 v[2][4096]; } kv;  // 32 KB
    float m[4][64][17];                                // 17.4 KB (epilogue)
  } smem;

  const int tid = threadIdx.x;
  const int wid = tid >> 6, lane = tid & 63;
  const int l31 = lane & 31, g2 = lane >> 5;
  const int ig = wid & 3, jsub = wid >> 2;

  // bijective XCD swizzle: 576 blocks = 8 XCD x 72; each XCD gets 4 heads
  const int bid = blockIdx.x;
  const int wg = (bid & 7) * 72 + (bid >> 3);
  const int bh = wg / 18, it = wg % 18;
  const int b = bh >> 2, n = bh & 3;
  const int i0w = it * 128 + ig * 32;

  const bf16* qb = qt + (size_t)bh * NHW * HD;
  const bf16* kb = kt + (size_t)bh * NHW * HD;
  const bf16* vb = vv + (size_t)bh * HD * NHW;

  // staging: 512 thr -> (r0 = row 0..63, cs = chunk 0..7), 1 K + 1 V chunk
  const int r0 = tid >> 3, cs = tid & 7;
  const bf16* kg = kb + r0 * HD + cs * 8;
  const bf16* vg = vb + (size_t)r0 * NHW + cs * 8;
#define EOFF(c, row) ((c) * 512 + ((((row) + (c)) & 63) << 3))
  const int lw = EOFF(cs, r0);

  int ksw[4];
#pragma unroll
  for (int kk = 0; kk < 4; ++kk) ksw[kk] = EOFF(2 * kk + g2, jsub * 32 + l31);
  int vsw0[2], vsw1[2];
#pragma unroll
  for (int J = 0; J < 2; ++J) {
    int c = jsub * 4 + J * 2 + g2;
    vsw0[J] = EOFF(c, l31);
    vsw1[J] = EOFF(c, l31 + 32);
  }
#undef EOFF

  // Q fragments: B-frag col i=l31, d = 16*kk + 8*g2 + e
  bf16x8 q[4];
#pragma unroll
  for (int kk = 0; kk < 4; ++kk)
    q[kk] = *reinterpret_cast<const bf16x8*>(qb + (i0w + l31) * HD + kk * 16 + g2 * 8);

  f32x16 acc0 = {}, acc1 = {};
  float l_r = 0.f;

  // prologue: stage tile 0 into buf 0
  {
    bf16x8 a = *reinterpret_cast<const bf16x8*>(kg);
    bf16x8 d = *reinterpret_cast<const bf16x8*>(vg);
    *reinterpret_cast<bf16x8*>(&smem.kv.k[0][lw]) = a;
    *reinterpret_cast<bf16x8*>(&smem.kv.v[0][lw]) = d;
  }
  asm volatile("s_waitcnt lgkmcnt(0)" ::: "memory");
  __builtin_amdgcn_s_barrier();

  for (int t = 0; t < 36; ++t) {
    const int cur = t & 1;
    bf16x8 kr, vr;
    if (t < 35) {  // issue next-tile global loads early (hide under compute)
      kr = *reinterpret_cast<const bf16x8*>(kg + (t + 1) * (64 * HD));
      vr = *reinterpret_cast<const bf16x8*>(vg + (t + 1) * 64);
    }
    const bf16* kc = smem.kv.k[cur];
    const bf16* vc = smem.kv.v[cur];

    // S^T = K . Q^T over this wave's 32-j subtile
    f32x16 s = {};
    __builtin_amdgcn_s_setprio(1);
#pragma unroll
    for (int kk = 0; kk < 4; ++kk) {
      bf16x8 kf = *reinterpret_cast<const bf16x8*>(kc + ksw[kk]);
      s = MFMA32(kf, q[kk], s);
    }
    __builtin_amdgcn_s_setprio(0);

    // zero-max softmax: P = 2^s (raw v_exp_f32), lane-local partial sum
    u32 P[8];
    float la = 0.f, lb = 0.f;
#pragma unroll
    for (int m = 0; m < 8; ++m) {
      float e0 = fexp2(s[2 * m]);
      float e1 = fexp2(s[2 * m + 1]);
      la += e0;
      lb += e1;
      u32 pk;
      asm("v_cvt_pk_bf16_f32 %0, %1, %2" : "=v"(pk) : "v"(e0), "v"(e1));
      P[m] = pk;
    }
    l_r += la + lb;

    // PV: build B-frags in regs via permlane32_swap, accumulate O^T
#pragma unroll
    for (int J = 0; J < 2; ++J) {
      u32 w0 = P[4 * J], w2 = P[4 * J + 2];
      asm("v_permlane32_swap_b32 %0, %1" : "+v"(w0), "+v"(w2));
      u32 w1 = P[4 * J + 1], w3 = P[4 * J + 3];
      asm("v_permlane32_swap_b32 %0, %1" : "+v"(w1), "+v"(w3));
      i32x4 wv;
      wv[0] = (int)w0; wv[1] = (int)w1; wv[2] = (int)w2; wv[3] = (int)w3;
      bf16x8 pf = __builtin_bit_cast(bf16x8, wv);
      bf16x8 v0 = *reinterpret_cast<const bf16x8*>(vc + vsw0[J]);
      bf16x8 v1 = *reinterpret_cast<const bf16x8*>(vc + vsw1[J]);
      __builtin_amdgcn_s_setprio(1);
      acc0 = MFMA32(v0, pf, acc0);
      acc1 = MFMA32(v1, pf, acc1);
      __builtin_amdgcn_s_setprio(0);
    }

    if (t < 35) {  // write staged regs into other buffer
      const int nb = cur ^ 1;
      *reinterpret_cast<bf16x8*>(&smem.kv.k[nb][lw]) = kr;
      *reinterpret_cast<bf16x8*>(&smem.kv.v[nb][lw]) = vr;
    }
    asm volatile("s_waitcnt lgkmcnt(0)" ::: "memory");
    __builtin_amdgcn_s_barrier();
  }

  // merge jsub halves (plain add, zero-max => no rescale), two phases
  if (jsub == 1) {
    float* mb = smem.m[ig][lane];
#pragma unroll
    for (int e = 0; e < 16; ++e) mb[e] = acc0[e];
    mb[16] = l_r;
  }
  __syncthreads();
  if (jsub == 0) {
    const float* mb = smem.m[ig][lane];
#pragma unroll
    for (int e = 0; e < 16; ++e) acc0[e] += mb[e];
    l_r += mb[16];
  }
  __syncthreads();
  if (jsub == 1) {
    float* mb = smem.m[ig][lane];
#pragma unroll
    for (int e = 0; e < 16; ++e) mb[e] = acc1[e];
  }
  __syncthreads();
  if (jsub == 0) {
    const float* mb = smem.m[ig][lane];
#pragma unroll
    for (int e = 0; e < 16; ++e) acc1[e] += mb[e];
    l_r += __shfl_xor(l_r, 32);
    const float inv = 1.0f / l_r;
    bf16* ob = att + ((size_t)(b * NHW) + i0w + l31) * NC + n * HD;
#pragma unroll
    for (int rq = 0; rq < 4; ++rq) {
      bf16x4 o0, o1;
#pragma unroll
      for (int c = 0; c < 4; ++c) {
        o0[c] = (bf16)(acc0[rq * 4 + c] * inv);
        o1[c] = (bf16)(acc1[rq * 4 + c] * inv);
      }
      *reinterpret_cast<bf16x4*>(ob + 8 * rq + 4 * g2) = o0;
      *reinterpret_cast<bf16x4*>(ob + 32 + 8 * rq + 4 * g2) = o1;
    }
  }
}

// ---------------- proj GEMM + bias + residual ----------------
__global__ __launch_bounds__(256) void k_proj(const bf16* __restrict__ att,
                                              const bf16* __restrict__ wp,
                                              const float* __restrict__ pb,
                                              const float* __restrict__ x,
                                              float* __restrict__ out) {
  int b = blockIdx.z;
  int i_base = blockIdx.x * 128;
  int o_base = blockIdx.y * 128;
  int t = threadIdx.x;
  int lane = t & 63, wid = t >> 6;
  int wm = (wid >> 1) * 64, wn = (wid & 1) * 64;
  int l15 = lane & 15, g = lane >> 4;
  const bf16* ab = wp + (o_base + wm + l15) * NC + g * 8;
  const bf16* bb = att + (b * NHW + i_base + wn + l15) * NC + g * 8;
  f32x4 acc[4][4] = {};
#pragma unroll 2
  for (int kc = 0; kc < 8; ++kc) {
    bf16x8 af[4], bf[4];
#pragma unroll
    for (int mf = 0; mf < 4; ++mf)
      af[mf] = *reinterpret_cast<const bf16x8*>(ab + mf * 16 * NC + kc * 32);
#pragma unroll
    for (int nf = 0; nf < 4; ++nf)
      bf[nf] = *reinterpret_cast<const bf16x8*>(bb + nf * 16 * NC + kc * 32);
#pragma unroll
    for (int mf = 0; mf < 4; ++mf)
#pragma unroll
      for (int nf = 0; nf < 4; ++nf)
        acc[mf][nf] = MFMA16(af[mf], bf[nf], acc[mf][nf]);
  }
  int orow0 = o_base + wm + g * 4;
#pragma unroll
  for (int mf = 0; mf < 4; ++mf)
#pragma unroll
    for (int r = 0; r < 4; ++r) {
      int o = orow0 + mf * 16 + r;
      float bias = pb[o];
      const float* xr = x + (b * NC + o) * NHW + i_base + wn;
      float* orow = out + (b * NC + o) * NHW + i_base + wn;
#pragma unroll
      for (int nf = 0; nf < 4; ++nf) {
        int i = nf * 16 + l15;
        orow[i] = acc[mf][nf][r] + bias + xr[i];
      }
    }
}

extern "C" void kernel_launch(void* const* d_in, const int* in_sizes, int n_in,
                              void* d_out, int out_size, void* d_ws, size_t ws_size,
                              hipStream_t stream) {
  const float* x    = (const float*)d_in[0];
  const float* gnw  = (const float*)d_in[1];
  const float* gnb  = (const float*)d_in[2];
  const float* qkvw = (const float*)d_in[3];
  const float* qkvb = (const float*)d_in[4];
  const float* pw   = (const float*)d_in[5];
  const float* pb   = (const float*)d_in[6];
  float* out = (float*)d_out;

  bf16* ws = (bf16*)d_ws;
  const size_t NE = (size_t)NB * NHW * NC;
  bf16* xnt = ws;
  bf16* qt  = ws + NE;
  bf16* kt  = ws + 2 * NE;
  bf16* vv  = ws + 3 * NE;
  bf16* att = ws + 4 * NE;
  bf16* wqb = ws + 5 * NE;
  bf16* wpb = wqb + 768 * 256;

  k_pre<<<512, 768, 0, stream>>>(x, gnw, gnb, qkvw, pw, xnt, wqb, wpb);
  k_qkv<<<dim3(18, 6, NB), 256, 0, stream>>>(xnt, wqb, qkvb, qt, kt, vv);
  k_attn<<<576, 512, 0, stream>>>(qt, kt, vv, att);
  k_proj<<<dim3(18, 2, NB), 256, 0, stream>>>(att, wpb, pb, x, out);
}